// Round 4
// baseline (247.219 us; speedup 1.0000x reference)
//
#include <hip/hip_runtime.h>
#include <cmath>

// Problem constants
#define B_   8
#define N_   4096
#define DIN1 64
#define DHID 128
#define DOUT2 64
#define MAXDEG 256

// ---------------- bf16 helpers (RNE pack, shift unpack) --------------------
__device__ __forceinline__ unsigned pack2bf(float a, float b) {
    unsigned ua = __float_as_uint(a), ub = __float_as_uint(b);
    ua = (ua + 0x7FFFu + ((ua >> 16) & 1u)) >> 16;
    ub = (ub + 0x7FFFu + ((ub >> 16) & 1u)) & 0xFFFF0000u;
    return ua | ub;          // lo half = a, hi half = b
}
__device__ __forceinline__ float2 unpack2bf(unsigned u) {
    return {__uint_as_float(u << 16), __uint_as_float(u & 0xFFFF0000u)};
}

template <int SH>
__device__ __forceinline__ float dpp_shr_add(float p) {
    int t = __builtin_amdgcn_update_dpp(0, __float_as_int(p),
                                        0x110 | SH, 0xF, 0xF, true);
    return p + __int_as_float(t);
}
// Row-sum lands on the TOP lane of each GRPL-lane subgroup.
template <int GRPL>
__device__ __forceinline__ float dpp_reduce(float p) {
    if constexpr (GRPL == 16) p = dpp_shr_add<8>(p);
    p = dpp_shr_add<4>(p);
    p = dpp_shr_add<2>(p);
    p = dpp_shr_add<1>(p);
    return p;   // valid on lane GRPL-1 of each subgroup
}

// ---------------------------------------------------------------------------
// Kernel 1: adjacency -> neighbor lists. Wave per row, ballot compaction.
// ---------------------------------------------------------------------------
__global__ __launch_bounds__(256) void k_build_csr(
    const float* __restrict__ graph, int* __restrict__ cnt, int* __restrict__ idx)
{
    const int wave = threadIdx.x >> 6;
    const int lane = threadIdx.x & 63;
    const int n = blockIdx.x * 4 + wave;
    const unsigned long long below_mask = (1ULL << lane) - 1ULL;

    const float4* __restrict__ row4 = (const float4*)(graph + (size_t)n * N_);
    int* __restrict__ myidx = idx + (size_t)n * MAXDEG;

    int base = 0;
    for (int it = 0; it < N_ / 256; ++it) {
        const int i4 = it * 64 + lane;
        float4 g = row4[i4];
        const int e = 4 * i4;
#pragma unroll
        for (int c = 0; c < 4; ++c) {
            const float gc = (c == 0) ? g.x : (c == 1) ? g.y : (c == 2) ? g.z : g.w;
            const unsigned long long mk = __ballot(gc != 0.0f);
            const int pos = base + __popcll(mk & below_mask);
            if (gc != 0.0f && pos < MAXDEG) myidx[pos] = e + c;
            base += __popcll(mk);
        }
    }
    if (lane == 0) cnt[n] = (base < MAXDEG) ? base : MAXDEG;
}

// ---------------------------------------------------------------------------
// Kernel 2a: linear1 with DUAL WRITE: fp32 h1 (exact, for attn1's accumulate
// + layers downstream) and bf16 h1b (for attn1's gather/score hot loop).
// [proven in the 237us baseline]
// ---------------------------------------------------------------------------
__global__ __launch_bounds__(256) void k_linear1(
    const float* __restrict__ x, const float* __restrict__ W,
    float* __restrict__ out, void* __restrict__ outb)
{
    constexpr int DIN = DIN1, DOUT = DHID;
    constexpr int CG = DOUT / 4;      // 32
    constexpr int RG = 256 / CG;      // 8
    constexpr int TR = 32 / RG;       // 4

    __shared__ float sWt[DIN][DOUT + 4];

    const int t = threadIdx.x;
    const float4* W4 = (const float4*)W;
    for (int i = t; i < DOUT * (DIN / 4); i += 256) {
        int kk = i / (DIN / 4);
        int d4 = i % (DIN / 4);
        float4 w = W4[i];
        sWt[4 * d4 + 0][kk] = w.x;
        sWt[4 * d4 + 1][kk] = w.y;
        sWt[4 * d4 + 2][kk] = w.z;
        sWt[4 * d4 + 3][kk] = w.w;
    }
    __syncthreads();

    const int rg = t / CG;
    const int c  = t % CG;
    const int base = blockIdx.x * 32;
    const float4* x4 = (const float4*)x;

    float acc[TR][4];
#pragma unroll
    for (int i = 0; i < TR; ++i)
#pragma unroll
        for (int j = 0; j < 4; ++j) acc[i][j] = 0.0f;

    for (int d4 = 0; d4 < DIN / 4; ++d4) {
        float4 xf[TR];
#pragma unroll
        for (int i = 0; i < TR; ++i)
            xf[i] = x4[(size_t)(base + rg * TR + i) * (DIN / 4) + d4];
        float4 wf[4];
#pragma unroll
        for (int dd = 0; dd < 4; ++dd)
            wf[dd] = *(const float4*)&sWt[4 * d4 + dd][4 * c];
#pragma unroll
        for (int i = 0; i < TR; ++i) {
            acc[i][0] += xf[i].x * wf[0].x + xf[i].y * wf[1].x + xf[i].z * wf[2].x + xf[i].w * wf[3].x;
            acc[i][1] += xf[i].x * wf[0].y + xf[i].y * wf[1].y + xf[i].z * wf[2].y + xf[i].w * wf[3].y;
            acc[i][2] += xf[i].x * wf[0].z + xf[i].y * wf[1].z + xf[i].z * wf[2].z + xf[i].w * wf[3].z;
            acc[i][3] += xf[i].x * wf[0].w + xf[i].y * wf[1].w + xf[i].z * wf[2].w + xf[i].w * wf[3].w;
        }
    }

#pragma unroll
    for (int i = 0; i < TR; ++i) {
        const size_t row = (size_t)(base + rg * TR + i);
        float4 o = {acc[i][0], acc[i][1], acc[i][2], acc[i][3]};
        ((float4*)out)[row * CG + c] = o;
        uint2 ob = {pack2bf(o.x, o.y), pack2bf(o.z, o.w)};
        *(uint2*)((char*)outb + row * (DOUT * 2) + c * 8) = ob;
    }
}

// ---------------------------------------------------------------------------
// Kernel 2b: plain fp32 register-tiled linear (layer 2). [proven]
// ---------------------------------------------------------------------------
template <int DIN, int DOUT>
__global__ __launch_bounds__(256) void k_linear(
    const float* __restrict__ x, const float* __restrict__ W,
    float* __restrict__ out)
{
    constexpr int CG = DOUT / 4;
    constexpr int RG = 256 / CG;
    constexpr int TR = 32 / RG;

    __shared__ float sWt[DIN][DOUT + 4];

    const int t = threadIdx.x;
    const float4* W4 = (const float4*)W;
    for (int i = t; i < DOUT * (DIN / 4); i += 256) {
        int kk = i / (DIN / 4);
        int d4 = i % (DIN / 4);
        float4 w = W4[i];
        sWt[4 * d4 + 0][kk] = w.x;
        sWt[4 * d4 + 1][kk] = w.y;
        sWt[4 * d4 + 2][kk] = w.z;
        sWt[4 * d4 + 3][kk] = w.w;
    }
    __syncthreads();

    const int rg = t / CG;
    const int c  = t % CG;
    const int base = blockIdx.x * 32;
    const float4* x4 = (const float4*)x;

    float acc[TR][4];
#pragma unroll
    for (int i = 0; i < TR; ++i)
#pragma unroll
        for (int j = 0; j < 4; ++j) acc[i][j] = 0.0f;

    for (int d4 = 0; d4 < DIN / 4; ++d4) {
        float4 xf[TR];
#pragma unroll
        for (int i = 0; i < TR; ++i)
            xf[i] = x4[(size_t)(base + rg * TR + i) * (DIN / 4) + d4];
        float4 wf[4];
#pragma unroll
        for (int dd = 0; dd < 4; ++dd)
            wf[dd] = *(const float4*)&sWt[4 * d4 + dd][4 * c];
#pragma unroll
        for (int i = 0; i < TR; ++i) {
            acc[i][0] += xf[i].x * wf[0].x + xf[i].y * wf[1].x + xf[i].z * wf[2].x + xf[i].w * wf[3].x;
            acc[i][1] += xf[i].x * wf[0].y + xf[i].y * wf[1].y + xf[i].z * wf[2].y + xf[i].w * wf[3].y;
            acc[i][2] += xf[i].x * wf[0].z + xf[i].y * wf[1].z + xf[i].z * wf[2].z + xf[i].w * wf[3].z;
            acc[i][3] += xf[i].x * wf[0].w + xf[i].y * wf[1].w + xf[i].z * wf[2].w + xf[i].w * wf[3].w;
        }
    }

#pragma unroll
    for (int i = 0; i < TR; ++i) {
        float4 o = {acc[i][0], acc[i][1], acc[i][2], acc[i][3]};
        ((float4*)out)[(size_t)(base + rg * TR + i) * CG + c] = o;
    }
}

// ---------------------------------------------------------------------------
// Kernel 3a: attn layer-1, BF16-GATHER / FP32-ACCUMULATE, GS=8 geometry.
// vs the 237us baseline: 8 streams of 8 lanes (16 dims/lane, 2 uint4/slice)
// instead of 4 streams of 16 lanes — amortizes dpp-reduce + per-step
// overhead over 2x neighbors (proven geometry: identical to k_attn2's).
// Scoring kept EXACTLY as the passing baseline: bf16 RNE storage, shift
// unpack, fixed-order serial FMA dot (float2 pairs so SLP may emit
// v_pk_fma_f32 — numerics unchanged either way, no reassociation at -O3).
// Self-score init uses the identical dot sequence on the identical stored
// bits -> p==m bit-exact -> one-hot path output bit-identical (taken path
// reloads the fp32 row and accumulates exactly). Exact torch
// masked_fill(s==0) semantics; all-masked fallback (fp32) unchanged.
// ---------------------------------------------------------------------------
__global__ __launch_bounds__(256) void k_attn1(
    const void* __restrict__ h16, const float* __restrict__ h32,
    const int* __restrict__ cnt, const int* __restrict__ idx,
    const float* __restrict__ bias, float* __restrict__ out)
{
    constexpr int RBb = DHID * 2;   // bf16 row bytes (256)
    constexpr int RBf = DHID * 4;   // fp32 row bytes (512)
    constexpr int GS  = 8;          // 8 streams of 8 lanes

    const int bid  = blockIdx.x;
    const int b    = bid & 7;                    // batch -> XCD pinning
    const int wave = threadIdx.x >> 6;
    const int lane = threadIdx.x & 63;
    const int n    = (bid >> 3) * 4 + wave;      // one query per wave
    const int grp  = lane >> 3;
    const int gl   = lane & 7;
    const int gtop = lane | 7;

    __shared__ int s_off[4][MAXDEG + 48];        // bf16 byte offsets

    const int k = cnt[n];
    const int* __restrict__ myidx = idx + (size_t)n * MAXDEG;
    for (int j = lane; j < k; j += 64) s_off[wave][j] = myidx[j] * RBb;
    for (int z = k + lane; z < k + 48; z += 64) s_off[wave][z] = 0;

    const char*  __restrict__ hb = (const char*)h16 + (size_t)b * N_ * RBb;
    const char*  __restrict__ hf = (const char*)h32 + (size_t)b * N_ * RBf;
    const int lb = gl * 32;                      // lane's bf16 byte slot (16 dims)

    // q fragment: 16 dims per lane, unpacked bf16 -> 8 float2
    float2 qc[8];
    {
        const uint4 q0 = *(const uint4*)(hb + (size_t)n * RBb + lb);
        const uint4 q1 = *(const uint4*)(hb + (size_t)n * RBb + lb + 16);
        const unsigned qw[8] = {q0.x, q0.y, q0.z, q0.w, q1.x, q1.y, q1.z, q1.w};
#pragma unroll
        for (int i = 0; i < 8; ++i) qc[i] = unpack2bf(qw[i]);
    }

    // fixed-order dot, two interleaved float2 chains; identical sequence for
    // self-init and loop -> bit-exact self score
    auto dotc = [&](const float2* c) -> float {
        float2 pa = {0.0f, 0.0f}, pb2 = {0.0f, 0.0f};
#pragma unroll
        for (int i = 0; i < 4; ++i) {
            pa.x  += qc[2 * i].x     * c[2 * i].x;
            pa.y  += qc[2 * i].y     * c[2 * i].y;
            pb2.x += qc[2 * i + 1].x * c[2 * i + 1].x;
            pb2.y += qc[2 * i + 1].y * c[2 * i + 1].y;
        }
        return (pa.x + pa.y) + (pb2.x + pb2.y);
    };

    // self-score init: m = ||q_bf16||^2 (identical op order to loop dot)
    float m;
    {
        float p = dotc(qc);
        p = dpp_reduce<8>(p);
        const float pb = __shfl(p, gtop, 64);
        m = (pb != 0.0f) ? pb : -INFINITY;
    }
    float mt = m - 100.0f;
    float s = 0.0f;
    float acc[16];
#pragma unroll
    for (int i = 0; i < 16; ++i) acc[i] = 0.0f;

    auto loadrow = [&](uint4 (&r)[2], int off) {
        const char* hm = hb + off + lb;
        r[0] = *(const uint4*)hm;
        r[1] = *(const uint4*)(hm + 16);
    };
    // taken path accumulates from the FP32 row (off is the bf16 offset;
    // fp32 offset = 2*off since RBf = 2*RBb)
    auto process = [&](const uint4 (&cur)[2], int off) {
        const unsigned cw[8] = {cur[0].x, cur[0].y, cur[0].z, cur[0].w,
                                cur[1].x, cur[1].y, cur[1].z, cur[1].w};
        float2 c[8];
#pragma unroll
        for (int i = 0; i < 8; ++i) c[i] = unpack2bf(cw[i]);
        float p = dotc(c);
        p = dpp_reduce<8>(p);
        if (__builtin_expect((__ballot(p > mt) & 0x8080808080808080ULL) != 0ULL, 0)) {
            const float pb = __shfl(p, gtop, 64);
            const bool valid = (pb != 0.0f);      // dot==0 => masked (torch)
            const float pm   = valid ? pb : m;
            const float newm = fmaxf(m, pm);
            const float f = (m == newm) ? 1.0f : __expf(m - newm);
            const float e = valid ? __expf(pb - newm) : 0.0f;
            s = s * f + e;
            // fp32 reload of this row's lane slice (dims [16gl, 16gl+16))
            const float4* fr = (const float4*)(hf + 2 * (size_t)off + (size_t)64 * gl);
#pragma unroll
            for (int i2 = 0; i2 < 4; ++i2) {
                const float4 v = fr[i2];
                acc[4 * i2 + 0] = acc[4 * i2 + 0] * f + e * v.x;
                acc[4 * i2 + 1] = acc[4 * i2 + 1] * f + e * v.y;
                acc[4 * i2 + 2] = acc[4 * i2 + 2] * f + e * v.z;
                acc[4 * i2 + 3] = acc[4 * i2 + 3] * f + e * v.w;
            }
            m = newm;
            mt = m - 100.0f;
        }
    };

    // depth-2 data + depth-4 offset pipeline; per-buffer offsets carried
    {
        uint4 r0[2], r1[2], r2[2];
        int u0, u1, u2, oA, oB, oC;
        oA = s_off[wave][grp + 2 * GS];
        oB = s_off[wave][grp + 3 * GS];
        u0 = s_off[wave][grp];
        loadrow(r0, u0);
        u1 = s_off[wave][grp + GS];
        loadrow(r1, u1);
        int j = grp;
        while (j < k) {
            oC = s_off[wave][j + 4 * GS];
            u2 = oA; loadrow(r2, u2);
            process(r0, u0);
            j += GS; if (j >= k) break;
            oA = s_off[wave][j + 4 * GS];
            u0 = oB; loadrow(r0, u0);
            process(r1, u1);
            j += GS; if (j >= k) break;
            oB = s_off[wave][j + 4 * GS];
            u1 = oC; loadrow(r1, u1);
            process(r2, u2);
            j += GS;
        }
    }

    // merge the 8 subgroup states (xor 8, 16, 32; lane&7 preserved)
#pragma unroll
    for (int mask = 8; mask <= 32; mask <<= 1) {
        const float m2 = __shfl_xor(m, mask, 64);
        const float s2 = __shfl_xor(s, mask, 64);
        float a2[16];
#pragma unroll
        for (int i = 0; i < 16; ++i) a2[i] = __shfl_xor(acc[i], mask, 64);
        const float mm = fmaxf(m, m2);
        const float f1 = (m  == mm) ? 1.0f : __expf(m  - mm);
        const float f2 = (m2 == mm) ? 1.0f : __expf(m2 - mm);
        s = s * f1 + s2 * f2;
#pragma unroll
        for (int i = 0; i < 16; ++i) acc[i] = acc[i] * f1 + a2[i] * f2;
        m = mm;
    }

    if (s > 0.0f) {
        if (grp == 0) {
            const float4* bias4 = (const float4*)bias;
            const float inv = 1.0f / s;
            float4* orow = (float4*)out + ((size_t)b * N_ + n) * (DHID / 4) + 4 * gl;
#pragma unroll
            for (int i = 0; i < 4; ++i) {
                const float4 bi = bias4[4 * gl + i];
                float4 o;
                o.x = fmaxf(acc[4 * i + 0] * inv + bi.x, 0.0f);
                o.y = fmaxf(acc[4 * i + 1] * inv + bi.y, 0.0f);
                o.z = fmaxf(acc[4 * i + 2] * inv + bi.z, 0.0f);
                o.w = fmaxf(acc[4 * i + 3] * inv + bi.w, 0.0f);
                orow[i] = o;
            }
        }
    } else {
        // RARE (all masked): uniform softmax -> column mean of fp32 h[b]
        const float4* hf4 = (const float4*)hf;
        const int sl = lane % 32;
        const int rs = lane / 32;
        float4 a = {0.0f, 0.0f, 0.0f, 0.0f};
        for (int row = rs; row < N_; row += 2) {
            float4 v = hf4[(size_t)row * 32 + sl];
            a.x += v.x; a.y += v.y; a.z += v.z; a.w += v.w;
        }
        a.x += __shfl_xor(a.x, 32, 64);
        a.y += __shfl_xor(a.y, 32, 64);
        a.z += __shfl_xor(a.z, 32, 64);
        a.w += __shfl_xor(a.w, 32, 64);
        if (lane < 32) {
            constexpr float invN = 1.0f / (float)N_;
            const float4 bi = ((const float4*)bias)[sl];
            float4 o;
            o.x = fmaxf(a.x * invN + bi.x, 0.0f);
            o.y = fmaxf(a.y * invN + bi.y, 0.0f);
            o.z = fmaxf(a.z * invN + bi.z, 0.0f);
            o.w = fmaxf(a.w * invN + bi.w, 0.0f);
            ((float4*)out)[((size_t)b * N_ + n) * 32 + sl] = o;
        }
    }
}

// ---------------------------------------------------------------------------
// Kernel 3b: attn layer-2, pure fp32 (proven; D=64, 8-lane streams).
// ---------------------------------------------------------------------------
__global__ __launch_bounds__(256) void k_attn2(
    const float* __restrict__ h, const int* __restrict__ cnt,
    const int* __restrict__ idx, const float* __restrict__ bias,
    float* __restrict__ out)
{
    constexpr int D  = DOUT2;
    constexpr int V  = D / 4;                    // 16
    constexpr int GS = 8;                        // 8 streams of 8 lanes
    constexpr int RB = D * 4;                    // 256

    const int bid  = blockIdx.x;
    const int b    = bid & 7;
    const int wave = threadIdx.x >> 6;
    const int lane = threadIdx.x & 63;
    const int n    = (bid >> 3) * 4 + wave;
    const int grp  = lane >> 3;
    const int gl   = lane & 7;
    const int gtop = lane | 7;

    __shared__ int s_off[4][MAXDEG + 48];

    const int k = cnt[n];
    const int* __restrict__ myidx = idx + (size_t)n * MAXDEG;
    for (int j = lane; j < k; j += 64) s_off[wave][j] = myidx[j] * RB;
    for (int z = k + lane; z < k + 48; z += 64) s_off[wave][z] = 0;

    const char* __restrict__ hb = (const char*)h + (size_t)b * N_ * RB;
    const int lb = gl * 16;

    float4 qf[2];
#pragma unroll
    for (int i = 0; i < 2; ++i)
        qf[i] = *(const float4*)(hb + (size_t)n * RB + lb + 128 * i);

    float m;
    {
        float p = 0.0f;
#pragma unroll
        for (int i = 0; i < 2; ++i)
            p += qf[i].x * qf[i].x + qf[i].y * qf[i].y
               + qf[i].z * qf[i].z + qf[i].w * qf[i].w;
        p = dpp_reduce<8>(p);
        const float pb = __shfl(p, gtop, 64);
        m = (pb != 0.0f) ? pb : -INFINITY;
    }
    float mt = m - 100.0f;
    float s = 0.0f;
    float4 acc[2];
#pragma unroll
    for (int i = 0; i < 2; ++i) acc[i] = {0.0f, 0.0f, 0.0f, 0.0f};

    auto loadrow = [&](float4 (&r)[2], int off) {
        const char* hm = hb + off;
#pragma unroll
        for (int i = 0; i < 2; ++i) r[i] = *(const float4*)(hm + lb + 128 * i);
    };
    auto process = [&](const float4 (&cur)[2]) {
        float p = 0.0f;
#pragma unroll
        for (int i = 0; i < 2; ++i)
            p += qf[i].x * cur[i].x + qf[i].y * cur[i].y
               + qf[i].z * cur[i].z + qf[i].w * cur[i].w;
        p = dpp_reduce<8>(p);
        if (__builtin_expect((__ballot(p > mt) & 0x8080808080808080ULL) != 0ULL, 0)) {
            const float pb = __shfl(p, gtop, 64);
            const bool valid = (pb != 0.0f);
            const float pm   = valid ? pb : m;
            const float newm = fmaxf(m, pm);
            const float f = (m == newm) ? 1.0f : __expf(m - newm);
            const float e = valid ? __expf(pb - newm) : 0.0f;
            s = s * f + e;
#pragma unroll
            for (int i = 0; i < 2; ++i) {
                acc[i].x = acc[i].x * f + e * cur[i].x;
                acc[i].y = acc[i].y * f + e * cur[i].y;
                acc[i].z = acc[i].z * f + e * cur[i].z;
                acc[i].w = acc[i].w * f + e * cur[i].w;
            }
            m = newm;
            mt = m - 100.0f;
        }
    };

    {
        float4 r0[2], r1[2], r2[2];
        int oA = s_off[wave][grp + 2 * GS];
        int oB = s_off[wave][grp + 3 * GS];
        int oC;
        loadrow(r0, s_off[wave][grp]);
        loadrow(r1, s_off[wave][grp + GS]);
        int j = grp;
        while (j < k) {
            oC = s_off[wave][j + 4 * GS];
            loadrow(r2, oA);
            process(r0);
            j += GS; if (j >= k) break;
            oA = s_off[wave][j + 4 * GS];
            loadrow(r0, oB);
            process(r1);
            j += GS; if (j >= k) break;
            oB = s_off[wave][j + 4 * GS];
            loadrow(r1, oC);
            process(r2);
            j += GS;
        }
    }

#pragma unroll
    for (int mask = 8; mask <= 32; mask <<= 1) {
        const float m2 = __shfl_xor(m, mask, 64);
        const float s2 = __shfl_xor(s, mask, 64);
        float4 a2[2];
#pragma unroll
        for (int i = 0; i < 2; ++i) {
            a2[i].x = __shfl_xor(acc[i].x, mask, 64);
            a2[i].y = __shfl_xor(acc[i].y, mask, 64);
            a2[i].z = __shfl_xor(acc[i].z, mask, 64);
            a2[i].w = __shfl_xor(acc[i].w, mask, 64);
        }
        const float mm = fmaxf(m, m2);
        const float f1 = (m  == mm) ? 1.0f : __expf(m  - mm);
        const float f2 = (m2 == mm) ? 1.0f : __expf(m2 - mm);
        s = s * f1 + s2 * f2;
#pragma unroll
        for (int i = 0; i < 2; ++i) {
            acc[i].x = acc[i].x * f1 + a2[i].x * f2;
            acc[i].y = acc[i].y * f1 + a2[i].y * f2;
            acc[i].z = acc[i].z * f1 + a2[i].z * f2;
            acc[i].w = acc[i].w * f1 + a2[i].w * f2;
        }
        m = mm;
    }

    if (s > 0.0f) {
        if (grp == 0) {
            const float4* bias4 = (const float4*)bias;
            const float inv = 1.0f / s;
#pragma unroll
            for (int i = 0; i < 2; ++i) {
                const float4 bi = bias4[gl + 8 * i];
                float4 o;
                o.x = acc[i].x * inv + bi.x;
                o.y = acc[i].y * inv + bi.y;
                o.z = acc[i].z * inv + bi.z;
                o.w = acc[i].w * inv + bi.w;
                ((float4*)out)[((size_t)b * N_ + n) * V + gl + 8 * i] = o;
            }
        }
    } else {
        const float4* hb4 = (const float4*)hb;
        const int sl = lane % V;
        const int rs = lane / V;
        float4 a = {0.0f, 0.0f, 0.0f, 0.0f};
        for (int row = rs; row < N_; row += 4) {
            float4 v = hb4[(size_t)row * V + sl];
            a.x += v.x; a.y += v.y; a.z += v.z; a.w += v.w;
        }
#pragma unroll
        for (int mask = 16; mask <= 32; mask <<= 1) {
            a.x += __shfl_xor(a.x, mask, 64);
            a.y += __shfl_xor(a.y, mask, 64);
            a.z += __shfl_xor(a.z, mask, 64);
            a.w += __shfl_xor(a.w, mask, 64);
        }
        if (lane < V) {
            constexpr float invN = 1.0f / (float)N_;
            const float4 bi = ((const float4*)bias)[sl];
            float4 o;
            o.x = a.x * invN + bi.x;
            o.y = a.y * invN + bi.y;
            o.z = a.z * invN + bi.z;
            o.w = a.w * invN + bi.w;
            ((float4*)out)[((size_t)b * N_ + n) * V + sl] = o;
        }
    }
}

// ---------------------------------------------------------------------------
// Launch
// ---------------------------------------------------------------------------
extern "C" void kernel_launch(void* const* d_in, const int* in_sizes, int n_in,
                              void* d_out, int out_size, void* d_ws, size_t ws_size,
                              hipStream_t stream) {
    (void)in_sizes; (void)n_in; (void)out_size; (void)ws_size;

    const float* flow_x = (const float*)d_in[0];
    const float* graph  = (const float*)d_in[1];
    const float* W1     = (const float*)d_in[2];
    const float* b1     = (const float*)d_in[3];
    const float* W2     = (const float*)d_in[4];
    const float* b2     = (const float*)d_in[5];
    float* out = (float*)d_out;

    char* p = (char*)d_ws;
    auto carve = [&](size_t bytes) -> void* {
        void* r = (void*)p;
        p += (bytes + 255) & ~(size_t)255;
        return r;
    };
    int*   nbr_cnt = (int*)carve((size_t)N_ * sizeof(int));
    int*   nbr_idx = (int*)carve((size_t)N_ * MAXDEG * sizeof(int));
    float* h1      = (float*)carve((size_t)B_ * N_ * DHID * sizeof(float));
    void*  h1b     = carve((size_t)B_ * N_ * DHID * 2);   // bf16 copy
    float* x2      = (float*)carve((size_t)B_ * N_ * DHID * sizeof(float));
    float* h2      = (float*)carve((size_t)B_ * N_ * DOUT2 * sizeof(float));

    // 1. adjacency -> neighbor lists
    k_build_csr<<<N_ / 4, 256, 0, stream>>>(graph, nbr_cnt, nbr_idx);

    // 2. layer 1 linear: fp32 h1 + bf16 h1b (dual write)
    k_linear1<<<(B_ * N_) / 32, 256, 0, stream>>>(flow_x, W1, h1, h1b);

    // 3. layer 1 attention: bf16 gather/score (GS=8), fp32 accumulate -> x2
    k_attn1<<<N_ * B_ / 4, 256, 0, stream>>>(h1b, h1, nbr_cnt, nbr_idx, b1, x2);

    // 4. layer 2 linear (fp32)
    k_linear<DHID, DOUT2><<<(B_ * N_) / 32, 256, 0, stream>>>(x2, W2, h2);

    // 5. layer 2 attention (fp32) -> d_out  ([B,N,1,64] flat-identical)
    k_attn2<<<N_ * B_ / 4, 256, 0, stream>>>(h2, nbr_cnt, nbr_idx, b2, out);
}

// Round 5
// 244.493 us; speedup vs baseline: 1.0111x; 1.0111x over previous
//
#include <hip/hip_runtime.h>
#include <cmath>

// Problem constants
#define B_   8
#define N_   4096
#define DIN1 64
#define DHID 128
#define DOUT2 64
#define MAXDEG 256

// ---------------- bf16 helpers (RNE pack, shift unpack) --------------------
__device__ __forceinline__ unsigned pack2bf(float a, float b) {
    unsigned ua = __float_as_uint(a), ub = __float_as_uint(b);
    ua = (ua + 0x7FFFu + ((ua >> 16) & 1u)) >> 16;
    ub = (ub + 0x7FFFu + ((ub >> 16) & 1u)) & 0xFFFF0000u;
    return ua | ub;          // lo half = a, hi half = b
}
__device__ __forceinline__ float2 unpack2bf(unsigned u) {
    return {__uint_as_float(u << 16), __uint_as_float(u & 0xFFFF0000u)};
}

template <int SH>
__device__ __forceinline__ float dpp_shr_add(float p) {
    int t = __builtin_amdgcn_update_dpp(0, __float_as_int(p),
                                        0x110 | SH, 0xF, 0xF, true);
    return p + __int_as_float(t);
}
// Row-sum lands on the TOP lane of each GRPL-lane subgroup.
template <int GRPL>
__device__ __forceinline__ float dpp_reduce(float p) {
    if constexpr (GRPL == 16) p = dpp_shr_add<8>(p);
    p = dpp_shr_add<4>(p);
    p = dpp_shr_add<2>(p);
    p = dpp_shr_add<1>(p);
    return p;   // valid on lane GRPL-1 of each subgroup
}

// ---------------------------------------------------------------------------
// Kernel 1: adjacency -> neighbor lists. Wave per row, ballot compaction.
// ---------------------------------------------------------------------------
__global__ __launch_bounds__(256) void k_build_csr(
    const float* __restrict__ graph, int* __restrict__ cnt, int* __restrict__ idx)
{
    const int wave = threadIdx.x >> 6;
    const int lane = threadIdx.x & 63;
    const int n = blockIdx.x * 4 + wave;
    const unsigned long long below_mask = (1ULL << lane) - 1ULL;

    const float4* __restrict__ row4 = (const float4*)(graph + (size_t)n * N_);
    int* __restrict__ myidx = idx + (size_t)n * MAXDEG;

    int base = 0;
    for (int it = 0; it < N_ / 256; ++it) {
        const int i4 = it * 64 + lane;
        float4 g = row4[i4];
        const int e = 4 * i4;
#pragma unroll
        for (int c = 0; c < 4; ++c) {
            const float gc = (c == 0) ? g.x : (c == 1) ? g.y : (c == 2) ? g.z : g.w;
            const unsigned long long mk = __ballot(gc != 0.0f);
            const int pos = base + __popcll(mk & below_mask);
            if (gc != 0.0f && pos < MAXDEG) myidx[pos] = e + c;
            base += __popcll(mk);
        }
    }
    if (lane == 0) cnt[n] = (base < MAXDEG) ? base : MAXDEG;
}

// ---------------------------------------------------------------------------
// Kernel 2a: linear1 with DUAL WRITE: fp32 h1 (exact, for attn1's accumulate
// + layers downstream) and bf16 h1b (for attn1's gather/score hot loop).
// [proven]
// ---------------------------------------------------------------------------
__global__ __launch_bounds__(256) void k_linear1(
    const float* __restrict__ x, const float* __restrict__ W,
    float* __restrict__ out, void* __restrict__ outb)
{
    constexpr int DIN = DIN1, DOUT = DHID;
    constexpr int CG = DOUT / 4;      // 32
    constexpr int RG = 256 / CG;      // 8
    constexpr int TR = 32 / RG;       // 4

    __shared__ float sWt[DIN][DOUT + 4];

    const int t = threadIdx.x;
    const float4* W4 = (const float4*)W;
    for (int i = t; i < DOUT * (DIN / 4); i += 256) {
        int kk = i / (DIN / 4);
        int d4 = i % (DIN / 4);
        float4 w = W4[i];
        sWt[4 * d4 + 0][kk] = w.x;
        sWt[4 * d4 + 1][kk] = w.y;
        sWt[4 * d4 + 2][kk] = w.z;
        sWt[4 * d4 + 3][kk] = w.w;
    }
    __syncthreads();

    const int rg = t / CG;
    const int c  = t % CG;
    const int base = blockIdx.x * 32;
    const float4* x4 = (const float4*)x;

    float acc[TR][4];
#pragma unroll
    for (int i = 0; i < TR; ++i)
#pragma unroll
        for (int j = 0; j < 4; ++j) acc[i][j] = 0.0f;

    for (int d4 = 0; d4 < DIN / 4; ++d4) {
        float4 xf[TR];
#pragma unroll
        for (int i = 0; i < TR; ++i)
            xf[i] = x4[(size_t)(base + rg * TR + i) * (DIN / 4) + d4];
        float4 wf[4];
#pragma unroll
        for (int dd = 0; dd < 4; ++dd)
            wf[dd] = *(const float4*)&sWt[4 * d4 + dd][4 * c];
#pragma unroll
        for (int i = 0; i < TR; ++i) {
            acc[i][0] += xf[i].x * wf[0].x + xf[i].y * wf[1].x + xf[i].z * wf[2].x + xf[i].w * wf[3].x;
            acc[i][1] += xf[i].x * wf[0].y + xf[i].y * wf[1].y + xf[i].z * wf[2].y + xf[i].w * wf[3].y;
            acc[i][2] += xf[i].x * wf[0].z + xf[i].y * wf[1].z + xf[i].z * wf[2].z + xf[i].w * wf[3].z;
            acc[i][3] += xf[i].x * wf[0].w + xf[i].y * wf[1].w + xf[i].z * wf[2].w + xf[i].w * wf[3].w;
        }
    }

#pragma unroll
    for (int i = 0; i < TR; ++i) {
        const size_t row = (size_t)(base + rg * TR + i);
        float4 o = {acc[i][0], acc[i][1], acc[i][2], acc[i][3]};
        ((float4*)out)[row * CG + c] = o;
        uint2 ob = {pack2bf(o.x, o.y), pack2bf(o.z, o.w)};
        *(uint2*)((char*)outb + row * (DOUT * 2) + c * 8) = ob;
    }
}

// ---------------------------------------------------------------------------
// Kernel 2b: plain fp32 register-tiled linear (layer 2). [proven]
// ---------------------------------------------------------------------------
template <int DIN, int DOUT>
__global__ __launch_bounds__(256) void k_linear(
    const float* __restrict__ x, const float* __restrict__ W,
    float* __restrict__ out)
{
    constexpr int CG = DOUT / 4;
    constexpr int RG = 256 / CG;
    constexpr int TR = 32 / RG;

    __shared__ float sWt[DIN][DOUT + 4];

    const int t = threadIdx.x;
    const float4* W4 = (const float4*)W;
    for (int i = t; i < DOUT * (DIN / 4); i += 256) {
        int kk = i / (DIN / 4);
        int d4 = i % (DIN / 4);
        float4 w = W4[i];
        sWt[4 * d4 + 0][kk] = w.x;
        sWt[4 * d4 + 1][kk] = w.y;
        sWt[4 * d4 + 2][kk] = w.z;
        sWt[4 * d4 + 3][kk] = w.w;
    }
    __syncthreads();

    const int rg = t / CG;
    const int c  = t % CG;
    const int base = blockIdx.x * 32;
    const float4* x4 = (const float4*)x;

    float acc[TR][4];
#pragma unroll
    for (int i = 0; i < TR; ++i)
#pragma unroll
        for (int j = 0; j < 4; ++j) acc[i][j] = 0.0f;

    for (int d4 = 0; d4 < DIN / 4; ++d4) {
        float4 xf[TR];
#pragma unroll
        for (int i = 0; i < TR; ++i)
            xf[i] = x4[(size_t)(base + rg * TR + i) * (DIN / 4) + d4];
        float4 wf[4];
#pragma unroll
        for (int dd = 0; dd < 4; ++dd)
            wf[dd] = *(const float4*)&sWt[4 * d4 + dd][4 * c];
#pragma unroll
        for (int i = 0; i < TR; ++i) {
            acc[i][0] += xf[i].x * wf[0].x + xf[i].y * wf[1].x + xf[i].z * wf[2].x + xf[i].w * wf[3].x;
            acc[i][1] += xf[i].x * wf[0].y + xf[i].y * wf[1].y + xf[i].z * wf[2].y + xf[i].w * wf[3].y;
            acc[i][2] += xf[i].x * wf[0].z + xf[i].y * wf[1].z + xf[i].z * wf[2].z + xf[i].w * wf[3].z;
            acc[i][3] += xf[i].x * wf[0].w + xf[i].y * wf[1].w + xf[i].z * wf[2].w + xf[i].w * wf[3].w;
        }
    }

#pragma unroll
    for (int i = 0; i < TR; ++i) {
        float4 o = {acc[i][0], acc[i][1], acc[i][2], acc[i][3]};
        ((float4*)out)[(size_t)(base + rg * TR + i) * CG + c] = o;
    }
}

// ---------------------------------------------------------------------------
// Kernel 3a: attn layer-1, BF16-GATHER / FP32-ACCUMULATE, GS=8 geometry with
// CONTIGUOUS-HALF addressing (the R4 fix): lane gl owns dims
// [8gl,8gl+8) U [64+8gl,64+8gl+8) -> its two uint4 loads sit at row+16gl and
// row+128+16gl. Each vmem instruction's 8 lanes are CONTIGUOUS 128B per row
// (2 cache lines/row/inst, 4 total = the floor), vs R4's stride-32B pattern
// that touched all 4 lines twice (8 line-requests/row -> request-bound,
// 67.8us). This mirrors the proven k_attn2 half-split addressing exactly.
// Scoring identical to the passing R4: bf16 RNE storage, shift unpack,
// fixed-order FMA dot; self-init shares the identical dot sequence on
// identical stored bits -> p==m bit-exact -> one-hot path exact (taken path
// reloads fp32). Exact torch masked_fill(s==0) semantics; fp32 fallback.
// ---------------------------------------------------------------------------
__global__ __launch_bounds__(256) void k_attn1(
    const void* __restrict__ h16, const float* __restrict__ h32,
    const int* __restrict__ cnt, const int* __restrict__ idx,
    const float* __restrict__ bias, float* __restrict__ out)
{
    constexpr int RBb = DHID * 2;   // bf16 row bytes (256)
    constexpr int RBf = DHID * 4;   // fp32 row bytes (512)
    constexpr int GS  = 8;          // 8 streams of 8 lanes

    const int bid  = blockIdx.x;
    const int b    = bid & 7;                    // batch -> XCD pinning
    const int wave = threadIdx.x >> 6;
    const int lane = threadIdx.x & 63;
    const int n    = (bid >> 3) * 4 + wave;      // one query per wave
    const int grp  = lane >> 3;
    const int gl   = lane & 7;
    const int gtop = lane | 7;

    __shared__ int s_off[4][MAXDEG + 48];        // bf16 byte offsets

    const int k = cnt[n];
    const int* __restrict__ myidx = idx + (size_t)n * MAXDEG;
    for (int j = lane; j < k; j += 64) s_off[wave][j] = myidx[j] * RBb;
    for (int z = k + lane; z < k + 48; z += 64) s_off[wave][z] = 0;

    const char*  __restrict__ hb = (const char*)h16 + (size_t)b * N_ * RBb;
    const char*  __restrict__ hf = (const char*)h32 + (size_t)b * N_ * RBf;
    const int lb = gl * 16;                      // 16B slot within each 128B half

    // q fragment: dims [8gl,8gl+8) and [64+8gl,64+8gl+8), unpacked -> 8 float2
    float2 qc[8];
    {
        const uint4 q0 = *(const uint4*)(hb + (size_t)n * RBb + lb);
        const uint4 q1 = *(const uint4*)(hb + (size_t)n * RBb + 128 + lb);
        const unsigned qw[8] = {q0.x, q0.y, q0.z, q0.w, q1.x, q1.y, q1.z, q1.w};
#pragma unroll
        for (int i = 0; i < 8; ++i) qc[i] = unpack2bf(qw[i]);
    }

    // fixed-order dot, two interleaved float2 chains; identical sequence for
    // self-init and loop -> bit-exact self score
    auto dotc = [&](const float2* c) -> float {
        float2 pa = {0.0f, 0.0f}, pb2 = {0.0f, 0.0f};
#pragma unroll
        for (int i = 0; i < 4; ++i) {
            pa.x  += qc[2 * i].x     * c[2 * i].x;
            pa.y  += qc[2 * i].y     * c[2 * i].y;
            pb2.x += qc[2 * i + 1].x * c[2 * i + 1].x;
            pb2.y += qc[2 * i + 1].y * c[2 * i + 1].y;
        }
        return (pa.x + pa.y) + (pb2.x + pb2.y);
    };

    // self-score init: m = ||q_bf16||^2 (identical op order to loop dot)
    float m;
    {
        float p = dotc(qc);
        p = dpp_reduce<8>(p);
        const float pb = __shfl(p, gtop, 64);
        m = (pb != 0.0f) ? pb : -INFINITY;
    }
    float mt = m - 100.0f;
    float s = 0.0f;
    float acc[16];   // [0..7] dims 8gl..8gl+8 ; [8..15] dims 64+8gl..+8
#pragma unroll
    for (int i = 0; i < 16; ++i) acc[i] = 0.0f;

    auto loadrow = [&](uint4 (&r)[2], int off) {
        const char* hm = hb + off + lb;
        r[0] = *(const uint4*)hm;          // dims [8gl, 8gl+8)
        r[1] = *(const uint4*)(hm + 128);  // dims [64+8gl, 64+8gl+8)
    };
    // taken path accumulates from the FP32 row (off is the bf16 offset;
    // fp32 offset = 2*off since RBf = 2*RBb)
    auto process = [&](const uint4 (&cur)[2], int off) {
        const unsigned cw[8] = {cur[0].x, cur[0].y, cur[0].z, cur[0].w,
                                cur[1].x, cur[1].y, cur[1].z, cur[1].w};
        float2 c[8];
#pragma unroll
        for (int i = 0; i < 8; ++i) c[i] = unpack2bf(cw[i]);
        float p = dotc(c);
        p = dpp_reduce<8>(p);
        if (__builtin_expect((__ballot(p > mt) & 0x8080808080808080ULL) != 0ULL, 0)) {
            const float pb = __shfl(p, gtop, 64);
            const bool valid = (pb != 0.0f);      // dot==0 => masked (torch)
            const float pm   = valid ? pb : m;
            const float newm = fmaxf(m, pm);
            const float f = (m == newm) ? 1.0f : __expf(m - newm);
            const float e = valid ? __expf(pb - newm) : 0.0f;
            s = s * f + e;
            // fp32 reload: dims [8gl,8gl+8) at byte 32gl, dims [64+8gl,..)
            // at byte 256+32gl
            const char* fb = hf + 2 * (size_t)off;
            const float4* fr0 = (const float4*)(fb + 32 * gl);
            const float4* fr1 = (const float4*)(fb + 256 + 32 * gl);
            const float4 v[4] = {fr0[0], fr0[1], fr1[0], fr1[1]};
#pragma unroll
            for (int i2 = 0; i2 < 4; ++i2) {
                acc[4 * i2 + 0] = acc[4 * i2 + 0] * f + e * v[i2].x;
                acc[4 * i2 + 1] = acc[4 * i2 + 1] * f + e * v[i2].y;
                acc[4 * i2 + 2] = acc[4 * i2 + 2] * f + e * v[i2].z;
                acc[4 * i2 + 3] = acc[4 * i2 + 3] * f + e * v[i2].w;
            }
            m = newm;
            mt = m - 100.0f;
        }
    };

    // depth-2 data + depth-4 offset pipeline; per-buffer offsets carried
    {
        uint4 r0[2], r1[2], r2[2];
        int u0, u1, u2, oA, oB, oC;
        oA = s_off[wave][grp + 2 * GS];
        oB = s_off[wave][grp + 3 * GS];
        u0 = s_off[wave][grp];
        loadrow(r0, u0);
        u1 = s_off[wave][grp + GS];
        loadrow(r1, u1);
        int j = grp;
        while (j < k) {
            oC = s_off[wave][j + 4 * GS];
            u2 = oA; loadrow(r2, u2);
            process(r0, u0);
            j += GS; if (j >= k) break;
            oA = s_off[wave][j + 4 * GS];
            u0 = oB; loadrow(r0, u0);
            process(r1, u1);
            j += GS; if (j >= k) break;
            oB = s_off[wave][j + 4 * GS];
            u1 = oC; loadrow(r1, u1);
            process(r2, u2);
            j += GS;
        }
    }

    // merge the 8 subgroup states (xor 8, 16, 32; lane&7 preserved)
#pragma unroll
    for (int mask = 8; mask <= 32; mask <<= 1) {
        const float m2 = __shfl_xor(m, mask, 64);
        const float s2 = __shfl_xor(s, mask, 64);
        float a2[16];
#pragma unroll
        for (int i = 0; i < 16; ++i) a2[i] = __shfl_xor(acc[i], mask, 64);
        const float mm = fmaxf(m, m2);
        const float f1 = (m  == mm) ? 1.0f : __expf(m  - mm);
        const float f2 = (m2 == mm) ? 1.0f : __expf(m2 - mm);
        s = s * f1 + s2 * f2;
#pragma unroll
        for (int i = 0; i < 16; ++i) acc[i] = acc[i] * f1 + a2[i] * f2;
        m = mm;
    }

    if (s > 0.0f) {
        if (grp == 0) {
            const float4* bias4 = (const float4*)bias;
            const float inv = 1.0f / s;
            float4* orow = (float4*)out + ((size_t)b * N_ + n) * (DHID / 4);
#pragma unroll
            for (int h = 0; h < 2; ++h) {       // half: dims 64h+8gl..
#pragma unroll
                for (int i = 0; i < 2; ++i) {
                    const int fi = 16 * h + 2 * gl + i;
                    const float4 bi = bias4[fi];
                    float4 o;
                    o.x = fmaxf(acc[8 * h + 4 * i + 0] * inv + bi.x, 0.0f);
                    o.y = fmaxf(acc[8 * h + 4 * i + 1] * inv + bi.y, 0.0f);
                    o.z = fmaxf(acc[8 * h + 4 * i + 2] * inv + bi.z, 0.0f);
                    o.w = fmaxf(acc[8 * h + 4 * i + 3] * inv + bi.w, 0.0f);
                    orow[fi] = o;
                }
            }
        }
    } else {
        // RARE (all masked): uniform softmax -> column mean of fp32 h[b]
        const float4* hf4 = (const float4*)hf;
        const int sl = lane % 32;
        const int rs = lane / 32;
        float4 a = {0.0f, 0.0f, 0.0f, 0.0f};
        for (int row = rs; row < N_; row += 2) {
            float4 v = hf4[(size_t)row * 32 + sl];
            a.x += v.x; a.y += v.y; a.z += v.z; a.w += v.w;
        }
        a.x += __shfl_xor(a.x, 32, 64);
        a.y += __shfl_xor(a.y, 32, 64);
        a.z += __shfl_xor(a.z, 32, 64);
        a.w += __shfl_xor(a.w, 32, 64);
        if (lane < 32) {
            constexpr float invN = 1.0f / (float)N_;
            const float4 bi = ((const float4*)bias)[sl];
            float4 o;
            o.x = fmaxf(a.x * invN + bi.x, 0.0f);
            o.y = fmaxf(a.y * invN + bi.y, 0.0f);
            o.z = fmaxf(a.z * invN + bi.z, 0.0f);
            o.w = fmaxf(a.w * invN + bi.w, 0.0f);
            ((float4*)out)[((size_t)b * N_ + n) * 32 + sl] = o;
        }
    }
}

// ---------------------------------------------------------------------------
// Kernel 3b: attn layer-2, pure fp32 (proven; D=64, 8-lane streams).
// ---------------------------------------------------------------------------
__global__ __launch_bounds__(256) void k_attn2(
    const float* __restrict__ h, const int* __restrict__ cnt,
    const int* __restrict__ idx, const float* __restrict__ bias,
    float* __restrict__ out)
{
    constexpr int D  = DOUT2;
    constexpr int V  = D / 4;                    // 16
    constexpr int GS = 8;                        // 8 streams of 8 lanes
    constexpr int RB = D * 4;                    // 256

    const int bid  = blockIdx.x;
    const int b    = bid & 7;
    const int wave = threadIdx.x >> 6;
    const int lane = threadIdx.x & 63;
    const int n    = (bid >> 3) * 4 + wave;
    const int grp  = lane >> 3;
    const int gl   = lane & 7;
    const int gtop = lane | 7;

    __shared__ int s_off[4][MAXDEG + 48];

    const int k = cnt[n];
    const int* __restrict__ myidx = idx + (size_t)n * MAXDEG;
    for (int j = lane; j < k; j += 64) s_off[wave][j] = myidx[j] * RB;
    for (int z = k + lane; z < k + 48; z += 64) s_off[wave][z] = 0;

    const char* __restrict__ hb = (const char*)h + (size_t)b * N_ * RB;
    const int lb = gl * 16;

    float4 qf[2];
#pragma unroll
    for (int i = 0; i < 2; ++i)
        qf[i] = *(const float4*)(hb + (size_t)n * RB + lb + 128 * i);

    float m;
    {
        float p = 0.0f;
#pragma unroll
        for (int i = 0; i < 2; ++i)
            p += qf[i].x * qf[i].x + qf[i].y * qf[i].y
               + qf[i].z * qf[i].z + qf[i].w * qf[i].w;
        p = dpp_reduce<8>(p);
        const float pb = __shfl(p, gtop, 64);
        m = (pb != 0.0f) ? pb : -INFINITY;
    }
    float mt = m - 100.0f;
    float s = 0.0f;
    float4 acc[2];
#pragma unroll
    for (int i = 0; i < 2; ++i) acc[i] = {0.0f, 0.0f, 0.0f, 0.0f};

    auto loadrow = [&](float4 (&r)[2], int off) {
        const char* hm = hb + off;
#pragma unroll
        for (int i = 0; i < 2; ++i) r[i] = *(const float4*)(hm + lb + 128 * i);
    };
    auto process = [&](const float4 (&cur)[2]) {
        float p = 0.0f;
#pragma unroll
        for (int i = 0; i < 2; ++i)
            p += qf[i].x * cur[i].x + qf[i].y * cur[i].y
               + qf[i].z * cur[i].z + qf[i].w * cur[i].w;
        p = dpp_reduce<8>(p);
        if (__builtin_expect((__ballot(p > mt) & 0x8080808080808080ULL) != 0ULL, 0)) {
            const float pb = __shfl(p, gtop, 64);
            const bool valid = (pb != 0.0f);
            const float pm   = valid ? pb : m;
            const float newm = fmaxf(m, pm);
            const float f = (m == newm) ? 1.0f : __expf(m - newm);
            const float e = valid ? __expf(pb - newm) : 0.0f;
            s = s * f + e;
#pragma unroll
            for (int i = 0; i < 2; ++i) {
                acc[i].x = acc[i].x * f + e * cur[i].x;
                acc[i].y = acc[i].y * f + e * cur[i].y;
                acc[i].z = acc[i].z * f + e * cur[i].z;
                acc[i].w = acc[i].w * f + e * cur[i].w;
            }
            m = newm;
            mt = m - 100.0f;
        }
    };

    {
        float4 r0[2], r1[2], r2[2];
        int oA = s_off[wave][grp + 2 * GS];
        int oB = s_off[wave][grp + 3 * GS];
        int oC;
        loadrow(r0, s_off[wave][grp]);
        loadrow(r1, s_off[wave][grp + GS]);
        int j = grp;
        while (j < k) {
            oC = s_off[wave][j + 4 * GS];
            loadrow(r2, oA);
            process(r0);
            j += GS; if (j >= k) break;
            oA = s_off[wave][j + 4 * GS];
            loadrow(r0, oB);
            process(r1);
            j += GS; if (j >= k) break;
            oB = s_off[wave][j + 4 * GS];
            loadrow(r1, oC);
            process(r2);
            j += GS;
        }
    }

#pragma unroll
    for (int mask = 8; mask <= 32; mask <<= 1) {
        const float m2 = __shfl_xor(m, mask, 64);
        const float s2 = __shfl_xor(s, mask, 64);
        float4 a2[2];
#pragma unroll
        for (int i = 0; i < 2; ++i) {
            a2[i].x = __shfl_xor(acc[i].x, mask, 64);
            a2[i].y = __shfl_xor(acc[i].y, mask, 64);
            a2[i].z = __shfl_xor(acc[i].z, mask, 64);
            a2[i].w = __shfl_xor(acc[i].w, mask, 64);
        }
        const float mm = fmaxf(m, m2);
        const float f1 = (m  == mm) ? 1.0f : __expf(m  - mm);
        const float f2 = (m2 == mm) ? 1.0f : __expf(m2 - mm);
        s = s * f1 + s2 * f2;
#pragma unroll
        for (int i = 0; i < 2; ++i) {
            acc[i].x = acc[i].x * f1 + a2[i].x * f2;
            acc[i].y = acc[i].y * f1 + a2[i].y * f2;
            acc[i].z = acc[i].z * f1 + a2[i].z * f2;
            acc[i].w = acc[i].w * f1 + a2[i].w * f2;
        }
        m = mm;
    }

    if (s > 0.0f) {
        if (grp == 0) {
            const float4* bias4 = (const float4*)bias;
            const float inv = 1.0f / s;
#pragma unroll
            for (int i = 0; i < 2; ++i) {
                const float4 bi = bias4[gl + 8 * i];
                float4 o;
                o.x = acc[i].x * inv + bi.x;
                o.y = acc[i].y * inv + bi.y;
                o.z = acc[i].z * inv + bi.z;
                o.w = acc[i].w * inv + bi.w;
                ((float4*)out)[((size_t)b * N_ + n) * V + gl + 8 * i] = o;
            }
        }
    } else {
        const float4* hb4 = (const float4*)hb;
        const int sl = lane % V;
        const int rs = lane / V;
        float4 a = {0.0f, 0.0f, 0.0f, 0.0f};
        for (int row = rs; row < N_; row += 4) {
            float4 v = hb4[(size_t)row * V + sl];
            a.x += v.x; a.y += v.y; a.z += v.z; a.w += v.w;
        }
#pragma unroll
        for (int mask = 16; mask <= 32; mask <<= 1) {
            a.x += __shfl_xor(a.x, mask, 64);
            a.y += __shfl_xor(a.y, mask, 64);
            a.z += __shfl_xor(a.z, mask, 64);
            a.w += __shfl_xor(a.w, mask, 64);
        }
        if (lane < V) {
            constexpr float invN = 1.0f / (float)N_;
            const float4 bi = ((const float4*)bias)[sl];
            float4 o;
            o.x = a.x * invN + bi.x;
            o.y = a.y * invN + bi.y;
            o.z = a.z * invN + bi.z;
            o.w = a.w * invN + bi.w;
            ((float4*)out)[((size_t)b * N_ + n) * V + sl] = o;
        }
    }
}

// ---------------------------------------------------------------------------
// Launch
// ---------------------------------------------------------------------------
extern "C" void kernel_launch(void* const* d_in, const int* in_sizes, int n_in,
                              void* d_out, int out_size, void* d_ws, size_t ws_size,
                              hipStream_t stream) {
    (void)in_sizes; (void)n_in; (void)out_size; (void)ws_size;

    const float* flow_x = (const float*)d_in[0];
    const float* graph  = (const float*)d_in[1];
    const float* W1     = (const float*)d_in[2];
    const float* b1     = (const float*)d_in[3];
    const float* W2     = (const float*)d_in[4];
    const float* b2     = (const float*)d_in[5];
    float* out = (float*)d_out;

    char* p = (char*)d_ws;
    auto carve = [&](size_t bytes) -> void* {
        void* r = (void*)p;
        p += (bytes + 255) & ~(size_t)255;
        return r;
    };
    int*   nbr_cnt = (int*)carve((size_t)N_ * sizeof(int));
    int*   nbr_idx = (int*)carve((size_t)N_ * MAXDEG * sizeof(int));
    float* h1      = (float*)carve((size_t)B_ * N_ * DHID * sizeof(float));
    void*  h1b     = carve((size_t)B_ * N_ * DHID * 2);   // bf16 copy
    float* x2      = (float*)carve((size_t)B_ * N_ * DHID * sizeof(float));
    float* h2      = (float*)carve((size_t)B_ * N_ * DOUT2 * sizeof(float));

    // 1. adjacency -> neighbor lists
    k_build_csr<<<N_ / 4, 256, 0, stream>>>(graph, nbr_cnt, nbr_idx);

    // 2. layer 1 linear: fp32 h1 + bf16 h1b (dual write)
    k_linear1<<<(B_ * N_) / 32, 256, 0, stream>>>(flow_x, W1, h1, h1b);

    // 3. layer 1 attention: bf16 gather/score (GS=8, half-split), fp32 acc
    k_attn1<<<N_ * B_ / 4, 256, 0, stream>>>(h1b, h1, nbr_cnt, nbr_idx, b1, x2);

    // 4. layer 2 linear (fp32)
    k_linear<DHID, DOUT2><<<(B_ * N_) / 32, 256, 0, stream>>>(x2, W2, h2);

    // 5. layer 2 attention (fp32) -> d_out  ([B,N,1,64] flat-identical)
    k_attn2<<<N_ * B_ / 4, 256, 0, stream>>>(h2, nbr_cnt, nbr_idx, b2, out);
}

// Round 6
// 237.959 us; speedup vs baseline: 1.0389x; 1.0275x over previous
//
#include <hip/hip_runtime.h>
#include <cmath>

// Problem constants
#define B_   8
#define N_   4096
#define DIN1 64
#define DHID 128
#define DOUT2 64
#define MAXDEG 256

// ---------------- bf16 helpers (RNE pack, shift unpack) --------------------
__device__ __forceinline__ unsigned pack2bf(float a, float b) {
    unsigned ua = __float_as_uint(a), ub = __float_as_uint(b);
    ua = (ua + 0x7FFFu + ((ua >> 16) & 1u)) >> 16;
    ub = (ub + 0x7FFFu + ((ub >> 16) & 1u)) & 0xFFFF0000u;
    return ua | ub;          // lo half = a, hi half = b
}
__device__ __forceinline__ float2 unpack2bf(unsigned u) {
    return {__uint_as_float(u << 16), __uint_as_float(u & 0xFFFF0000u)};
}
// LAZY unpack: hi element keeps the low-16 garbage bits (<=2^-7 relative
// mantissa perturbation, exponent untouched -> finite stays finite).
// Deterministic; used identically for q-init and loop -> self score exact.
__device__ __forceinline__ float2 lazy2bf(unsigned u) {
    return {__uint_as_float(u << 16), __uint_as_float(u)};
}

template <int SH>
__device__ __forceinline__ float dpp_shr_add(float p) {
    int t = __builtin_amdgcn_update_dpp(0, __float_as_int(p),
                                        0x110 | SH, 0xF, 0xF, true);
    return p + __int_as_float(t);
}
// Row-sum lands on the TOP lane of each GRPL-lane subgroup.
template <int GRPL>
__device__ __forceinline__ float dpp_reduce(float p) {
    if constexpr (GRPL == 16) p = dpp_shr_add<8>(p);
    p = dpp_shr_add<4>(p);
    p = dpp_shr_add<2>(p);
    p = dpp_shr_add<1>(p);
    return p;   // valid on lane GRPL-1 of each subgroup
}

// ---------------------------------------------------------------------------
// Kernel 1: adjacency -> neighbor lists. Wave per row, ballot compaction.
// ---------------------------------------------------------------------------
__global__ __launch_bounds__(256) void k_build_csr(
    const float* __restrict__ graph, int* __restrict__ cnt, int* __restrict__ idx)
{
    const int wave = threadIdx.x >> 6;
    const int lane = threadIdx.x & 63;
    const int n = blockIdx.x * 4 + wave;
    const unsigned long long below_mask = (1ULL << lane) - 1ULL;

    const float4* __restrict__ row4 = (const float4*)(graph + (size_t)n * N_);
    int* __restrict__ myidx = idx + (size_t)n * MAXDEG;

    int base = 0;
    for (int it = 0; it < N_ / 256; ++it) {
        const int i4 = it * 64 + lane;
        float4 g = row4[i4];
        const int e = 4 * i4;
#pragma unroll
        for (int c = 0; c < 4; ++c) {
            const float gc = (c == 0) ? g.x : (c == 1) ? g.y : (c == 2) ? g.z : g.w;
            const unsigned long long mk = __ballot(gc != 0.0f);
            const int pos = base + __popcll(mk & below_mask);
            if (gc != 0.0f && pos < MAXDEG) myidx[pos] = e + c;
            base += __popcll(mk);
        }
    }
    if (lane == 0) cnt[n] = (base < MAXDEG) ? base : MAXDEG;
}

// ---------------------------------------------------------------------------
// Kernel 2a: linear1 with DUAL WRITE: fp32 h1 (exact) + bf16 h1b. [proven]
// ---------------------------------------------------------------------------
__global__ __launch_bounds__(256) void k_linear1(
    const float* __restrict__ x, const float* __restrict__ W,
    float* __restrict__ out, void* __restrict__ outb)
{
    constexpr int DIN = DIN1, DOUT = DHID;
    constexpr int CG = DOUT / 4;      // 32
    constexpr int RG = 256 / CG;      // 8
    constexpr int TR = 32 / RG;       // 4

    __shared__ float sWt[DIN][DOUT + 4];

    const int t = threadIdx.x;
    const float4* W4 = (const float4*)W;
    for (int i = t; i < DOUT * (DIN / 4); i += 256) {
        int kk = i / (DIN / 4);
        int d4 = i % (DIN / 4);
        float4 w = W4[i];
        sWt[4 * d4 + 0][kk] = w.x;
        sWt[4 * d4 + 1][kk] = w.y;
        sWt[4 * d4 + 2][kk] = w.z;
        sWt[4 * d4 + 3][kk] = w.w;
    }
    __syncthreads();

    const int rg = t / CG;
    const int c  = t % CG;
    const int base = blockIdx.x * 32;
    const float4* x4 = (const float4*)x;

    float acc[TR][4];
#pragma unroll
    for (int i = 0; i < TR; ++i)
#pragma unroll
        for (int j = 0; j < 4; ++j) acc[i][j] = 0.0f;

    for (int d4 = 0; d4 < DIN / 4; ++d4) {
        float4 xf[TR];
#pragma unroll
        for (int i = 0; i < TR; ++i)
            xf[i] = x4[(size_t)(base + rg * TR + i) * (DIN / 4) + d4];
        float4 wf[4];
#pragma unroll
        for (int dd = 0; dd < 4; ++dd)
            wf[dd] = *(const float4*)&sWt[4 * d4 + dd][4 * c];
#pragma unroll
        for (int i = 0; i < TR; ++i) {
            acc[i][0] += xf[i].x * wf[0].x + xf[i].y * wf[1].x + xf[i].z * wf[2].x + xf[i].w * wf[3].x;
            acc[i][1] += xf[i].x * wf[0].y + xf[i].y * wf[1].y + xf[i].z * wf[2].y + xf[i].w * wf[3].y;
            acc[i][2] += xf[i].x * wf[0].z + xf[i].y * wf[1].z + xf[i].z * wf[2].z + xf[i].w * wf[3].z;
            acc[i][3] += xf[i].x * wf[0].w + xf[i].y * wf[1].w + xf[i].z * wf[2].w + xf[i].w * wf[3].w;
        }
    }

#pragma unroll
    for (int i = 0; i < TR; ++i) {
        const size_t row = (size_t)(base + rg * TR + i);
        float4 o = {acc[i][0], acc[i][1], acc[i][2], acc[i][3]};
        ((float4*)out)[row * CG + c] = o;
        uint2 ob = {pack2bf(o.x, o.y), pack2bf(o.z, o.w)};
        *(uint2*)((char*)outb + row * (DOUT * 2) + c * 8) = ob;
    }
}

// ---------------------------------------------------------------------------
// Kernel 2b: plain fp32 register-tiled linear (layer 2). [proven]
// ---------------------------------------------------------------------------
template <int DIN, int DOUT>
__global__ __launch_bounds__(256) void k_linear(
    const float* __restrict__ x, const float* __restrict__ W,
    float* __restrict__ out)
{
    constexpr int CG = DOUT / 4;
    constexpr int RG = 256 / CG;
    constexpr int TR = 32 / RG;

    __shared__ float sWt[DIN][DOUT + 4];

    const int t = threadIdx.x;
    const float4* W4 = (const float4*)W;
    for (int i = t; i < DOUT * (DIN / 4); i += 256) {
        int kk = i / (DIN / 4);
        int d4 = i % (DIN / 4);
        float4 w = W4[i];
        sWt[4 * d4 + 0][kk] = w.x;
        sWt[4 * d4 + 1][kk] = w.y;
        sWt[4 * d4 + 2][kk] = w.z;
        sWt[4 * d4 + 3][kk] = w.w;
    }
    __syncthreads();

    const int rg = t / CG;
    const int c  = t % CG;
    const int base = blockIdx.x * 32;
    const float4* x4 = (const float4*)x;

    float acc[TR][4];
#pragma unroll
    for (int i = 0; i < TR; ++i)
#pragma unroll
        for (int j = 0; j < 4; ++j) acc[i][j] = 0.0f;

    for (int d4 = 0; d4 < DIN / 4; ++d4) {
        float4 xf[TR];
#pragma unroll
        for (int i = 0; i < TR; ++i)
            xf[i] = x4[(size_t)(base + rg * TR + i) * (DIN / 4) + d4];
        float4 wf[4];
#pragma unroll
        for (int dd = 0; dd < 4; ++dd)
            wf[dd] = *(const float4*)&sWt[4 * d4 + dd][4 * c];
#pragma unroll
        for (int i = 0; i < TR; ++i) {
            acc[i][0] += xf[i].x * wf[0].x + xf[i].y * wf[1].x + xf[i].z * wf[2].x + xf[i].w * wf[3].x;
            acc[i][1] += xf[i].x * wf[0].y + xf[i].y * wf[1].y + xf[i].z * wf[2].y + xf[i].w * wf[3].y;
            acc[i][2] += xf[i].x * wf[0].z + xf[i].y * wf[1].z + xf[i].z * wf[2].z + xf[i].w * wf[3].z;
            acc[i][3] += xf[i].x * wf[0].w + xf[i].y * wf[1].w + xf[i].z * wf[2].w + xf[i].w * wf[3].w;
        }
    }

#pragma unroll
    for (int i = 0; i < TR; ++i) {
        float4 o = {acc[i][0], acc[i][1], acc[i][2], acc[i][3]};
        ((float4*)out)[(size_t)(base + rg * TR + i) * CG + c] = o;
    }
}

// ---------------------------------------------------------------------------
// Kernel 3a: attn layer-1 — PROVEN GS=4 structure (16-lane streams, 56.4us,
// 91% VALUBusy) with two VALU cuts on the dominant dot:
//  (a) lazy hi-unpack: raw word = hi-bf16 value with <=2^-7 mantissa garbage
//      (deterministic; identical treatment in q-init and loop -> self score
//      bit-exact -> one-hot path exact). Halves unpack insts.
//  (b) two float2 FMA chains (pk_fma-friendly, 4-deep ILP) instead of one
//      8-deep serial chain. Same fixed order in init and loop.
// Score noise ~±30 << 100 screen margin << layer-1 gaps (~1e3). Taken path
// reloads fp32 rows and accumulates exactly. Exact torch masked_fill(s==0)
// semantics; all-masked fp32 fallback unchanged.
// ---------------------------------------------------------------------------
__global__ __launch_bounds__(256) void k_attn1(
    const void* __restrict__ h16, const float* __restrict__ h32,
    const int* __restrict__ cnt, const int* __restrict__ idx,
    const float* __restrict__ bias, float* __restrict__ out)
{
    constexpr int RBb = DHID * 2;   // bf16 row bytes (256)
    constexpr int RBf = DHID * 4;   // fp32 row bytes (512)
    constexpr int GS  = 4;          // 4 streams of 16 lanes

    const int bid  = blockIdx.x;
    const int b    = bid & 7;                    // batch -> XCD pinning
    const int wave = threadIdx.x >> 6;
    const int lane = threadIdx.x & 63;
    const int n    = (bid >> 3) * 4 + wave;      // one query per wave
    const int grp  = lane >> 4;
    const int gl   = lane & 15;
    const int gtop = lane | 15;

    __shared__ int s_off[4][MAXDEG + 48];        // bf16 byte offsets

    const int k = cnt[n];
    const int* __restrict__ myidx = idx + (size_t)n * MAXDEG;
    for (int j = lane; j < k; j += 64) s_off[wave][j] = myidx[j] * RBb;
    for (int z = k + lane; z < k + 48; z += 64) s_off[wave][z] = 0;

    const char*  __restrict__ hb = (const char*)h16 + (size_t)b * N_ * RBb;
    const char*  __restrict__ hf = (const char*)h32 + (size_t)b * N_ * RBf;
    const int lb = gl * 16;                      // lane's bf16 byte slot (8 dims)

    // q fragment: 8 dims per lane, LAZY-unpacked bf16 -> 4 float2
    float2 qc[4];
    {
        const uint4 qu = *(const uint4*)(hb + (size_t)n * RBb + lb);
        qc[0] = lazy2bf(qu.x); qc[1] = lazy2bf(qu.y);
        qc[2] = lazy2bf(qu.z); qc[3] = lazy2bf(qu.w);
    }

    // fixed-order dot: two float2 chains (pk_fma-friendly); identical
    // sequence for self-init and loop -> bit-exact self score
    auto dotc = [&](const float2* c) -> float {
        float2 pa = {0.0f, 0.0f}, pb2 = {0.0f, 0.0f};
        pa.x  += qc[0].x * c[0].x;  pa.y  += qc[0].y * c[0].y;
        pb2.x += qc[1].x * c[1].x;  pb2.y += qc[1].y * c[1].y;
        pa.x  += qc[2].x * c[2].x;  pa.y  += qc[2].y * c[2].y;
        pb2.x += qc[3].x * c[3].x;  pb2.y += qc[3].y * c[3].y;
        return (pa.x + pa.y) + (pb2.x + pb2.y);
    };

    // self-score init: m = ||q_lazy||^2 (identical op order to loop dot)
    float m;
    {
        float p = dotc(qc);
        p = dpp_reduce<16>(p);
        const float pb = __shfl(p, gtop, 64);
        m = (pb != 0.0f) ? pb : -INFINITY;
    }
    float mt = m - 100.0f;
    float s = 0.0f;
    float acc8[8];
#pragma unroll
    for (int i = 0; i < 8; ++i) acc8[i] = 0.0f;

    // taken path accumulates from the FP32 row (off is the bf16 offset;
    // fp32 offset = 2*off since RBf = 2*RBb)
    auto process = [&](const uint4 cur, int off) {
        float2 c[4] = {lazy2bf(cur.x), lazy2bf(cur.y),
                       lazy2bf(cur.z), lazy2bf(cur.w)};
        float p = dotc(c);
        p = dpp_reduce<16>(p);
        if (__builtin_expect((__ballot(p > mt) & 0x8000800080008000ULL) != 0ULL, 0)) {
            const float pb = __shfl(p, gtop, 64);
            const bool valid = (pb != 0.0f);      // dot==0 => masked (torch)
            const float pm   = valid ? pb : m;
            const float newm = fmaxf(m, pm);
            const float f = (m == newm) ? 1.0f : __expf(m - newm);
            const float e = valid ? __expf(pb - newm) : 0.0f;
            s = s * f + e;
            // fp32 reload of this row's lane slice (dims [8gl, 8gl+8))
            const float4* fr = (const float4*)(hf + 2 * (size_t)off) + 2 * gl;
            const float4 lo = fr[0], hi = fr[1];
            const float f8[8] = {lo.x, lo.y, lo.z, lo.w, hi.x, hi.y, hi.z, hi.w};
#pragma unroll
            for (int i = 0; i < 8; ++i) acc8[i] = acc8[i] * f + e * f8[i];
            m = newm;
            mt = m - 100.0f;
        }
    };

    // depth-2 data + depth-4 offset pipeline; per-buffer offsets carried
    {
        uint4 r0, r1, r2;
        int u0, u1, u2, oA, oB, oC;
        oA = s_off[wave][grp + 2 * GS];
        oB = s_off[wave][grp + 3 * GS];
        u0 = s_off[wave][grp];
        r0 = *(const uint4*)(hb + u0 + lb);
        u1 = s_off[wave][grp + GS];
        r1 = *(const uint4*)(hb + u1 + lb);
        int j = grp;
        while (j < k) {
            oC = s_off[wave][j + 4 * GS];
            u2 = oA; r2 = *(const uint4*)(hb + u2 + lb);
            process(r0, u0);
            j += GS; if (j >= k) break;
            oA = s_off[wave][j + 4 * GS];
            u0 = oB; r0 = *(const uint4*)(hb + u0 + lb);
            process(r1, u1);
            j += GS; if (j >= k) break;
            oB = s_off[wave][j + 4 * GS];
            u1 = oC; r1 = *(const uint4*)(hb + u1 + lb);
            process(r2, u2);
            j += GS;
        }
    }

    // merge the 4 subgroup states (xor 16, 32)
#pragma unroll
    for (int mask = 16; mask <= 32; mask <<= 1) {
        const float m2 = __shfl_xor(m, mask, 64);
        const float s2 = __shfl_xor(s, mask, 64);
        float a2[8];
#pragma unroll
        for (int i = 0; i < 8; ++i) a2[i] = __shfl_xor(acc8[i], mask, 64);
        const float mm = fmaxf(m, m2);
        const float f1 = (m  == mm) ? 1.0f : __expf(m  - mm);
        const float f2 = (m2 == mm) ? 1.0f : __expf(m2 - mm);
        s = s * f1 + s2 * f2;
#pragma unroll
        for (int i = 0; i < 8; ++i) acc8[i] = acc8[i] * f1 + a2[i] * f2;
        m = mm;
    }

    if (s > 0.0f) {
        if (grp == 0) {
            const float4* bias4 = (const float4*)bias;
            const float4 b0 = bias4[2 * gl], b1 = bias4[2 * gl + 1];
            const float bi[8] = {b0.x, b0.y, b0.z, b0.w, b1.x, b1.y, b1.z, b1.w};
            const float inv = 1.0f / s;
            float4 lo, hi;
            lo.x = fmaxf(acc8[0] * inv + bi[0], 0.0f);
            lo.y = fmaxf(acc8[1] * inv + bi[1], 0.0f);
            lo.z = fmaxf(acc8[2] * inv + bi[2], 0.0f);
            lo.w = fmaxf(acc8[3] * inv + bi[3], 0.0f);
            hi.x = fmaxf(acc8[4] * inv + bi[4], 0.0f);
            hi.y = fmaxf(acc8[5] * inv + bi[5], 0.0f);
            hi.z = fmaxf(acc8[6] * inv + bi[6], 0.0f);
            hi.w = fmaxf(acc8[7] * inv + bi[7], 0.0f);
            float4* orow = (float4*)out + ((size_t)b * N_ + n) * (DHID / 4) + 2 * gl;
            orow[0] = lo;
            orow[1] = hi;
        }
    } else {
        // RARE (all masked): uniform softmax -> column mean of fp32 h[b]
        const float4* hf4 = (const float4*)hf;
        const int sl = lane % 32;
        const int rs = lane / 32;
        float4 a = {0.0f, 0.0f, 0.0f, 0.0f};
        for (int row = rs; row < N_; row += 2) {
            float4 v = hf4[(size_t)row * 32 + sl];
            a.x += v.x; a.y += v.y; a.z += v.z; a.w += v.w;
        }
        a.x += __shfl_xor(a.x, 32, 64);
        a.y += __shfl_xor(a.y, 32, 64);
        a.z += __shfl_xor(a.z, 32, 64);
        a.w += __shfl_xor(a.w, 32, 64);
        if (lane < 32) {
            constexpr float invN = 1.0f / (float)N_;
            const float4 bi = ((const float4*)bias)[sl];
            float4 o;
            o.x = fmaxf(a.x * invN + bi.x, 0.0f);
            o.y = fmaxf(a.y * invN + bi.y, 0.0f);
            o.z = fmaxf(a.z * invN + bi.z, 0.0f);
            o.w = fmaxf(a.w * invN + bi.w, 0.0f);
            ((float4*)out)[((size_t)b * N_ + n) * 32 + sl] = o;
        }
    }
}

// ---------------------------------------------------------------------------
// Kernel 3b: attn layer-2, pure fp32 (proven; D=64, 8-lane streams).
// ---------------------------------------------------------------------------
__global__ __launch_bounds__(256) void k_attn2(
    const float* __restrict__ h, const int* __restrict__ cnt,
    const int* __restrict__ idx, const float* __restrict__ bias,
    float* __restrict__ out)
{
    constexpr int D  = DOUT2;
    constexpr int V  = D / 4;                    // 16
    constexpr int GS = 8;                        // 8 streams of 8 lanes
    constexpr int RB = D * 4;                    // 256

    const int bid  = blockIdx.x;
    const int b    = bid & 7;
    const int wave = threadIdx.x >> 6;
    const int lane = threadIdx.x & 63;
    const int n    = (bid >> 3) * 4 + wave;
    const int grp  = lane >> 3;
    const int gl   = lane & 7;
    const int gtop = lane | 7;

    __shared__ int s_off[4][MAXDEG + 48];

    const int k = cnt[n];
    const int* __restrict__ myidx = idx + (size_t)n * MAXDEG;
    for (int j = lane; j < k; j += 64) s_off[wave][j] = myidx[j] * RB;
    for (int z = k + lane; z < k + 48; z += 64) s_off[wave][z] = 0;

    const char* __restrict__ hb = (const char*)h + (size_t)b * N_ * RB;
    const int lb = gl * 16;

    float4 qf[2];
#pragma unroll
    for (int i = 0; i < 2; ++i)
        qf[i] = *(const float4*)(hb + (size_t)n * RB + lb + 128 * i);

    float m;
    {
        float p = 0.0f;
#pragma unroll
        for (int i = 0; i < 2; ++i)
            p += qf[i].x * qf[i].x + qf[i].y * qf[i].y
               + qf[i].z * qf[i].z + qf[i].w * qf[i].w;
        p = dpp_reduce<8>(p);
        const float pb = __shfl(p, gtop, 64);
        m = (pb != 0.0f) ? pb : -INFINITY;
    }
    float mt = m - 100.0f;
    float s = 0.0f;
    float4 acc[2];
#pragma unroll
    for (int i = 0; i < 2; ++i) acc[i] = {0.0f, 0.0f, 0.0f, 0.0f};

    auto loadrow = [&](float4 (&r)[2], int off) {
        const char* hm = hb + off;
#pragma unroll
        for (int i = 0; i < 2; ++i) r[i] = *(const float4*)(hm + lb + 128 * i);
    };
    auto process = [&](const float4 (&cur)[2]) {
        float p = 0.0f;
#pragma unroll
        for (int i = 0; i < 2; ++i)
            p += qf[i].x * cur[i].x + qf[i].y * cur[i].y
               + qf[i].z * cur[i].z + qf[i].w * cur[i].w;
        p = dpp_reduce<8>(p);
        if (__builtin_expect((__ballot(p > mt) & 0x8080808080808080ULL) != 0ULL, 0)) {
            const float pb = __shfl(p, gtop, 64);
            const bool valid = (pb != 0.0f);
            const float pm   = valid ? pb : m;
            const float newm = fmaxf(m, pm);
            const float f = (m == newm) ? 1.0f : __expf(m - newm);
            const float e = valid ? __expf(pb - newm) : 0.0f;
            s = s * f + e;
#pragma unroll
            for (int i = 0; i < 2; ++i) {
                acc[i].x = acc[i].x * f + e * cur[i].x;
                acc[i].y = acc[i].y * f + e * cur[i].y;
                acc[i].z = acc[i].z * f + e * cur[i].z;
                acc[i].w = acc[i].w * f + e * cur[i].w;
            }
            m = newm;
            mt = m - 100.0f;
        }
    };

    {
        float4 r0[2], r1[2], r2[2];
        int oA = s_off[wave][grp + 2 * GS];
        int oB = s_off[wave][grp + 3 * GS];
        int oC;
        loadrow(r0, s_off[wave][grp]);
        loadrow(r1, s_off[wave][grp + GS]);
        int j = grp;
        while (j < k) {
            oC = s_off[wave][j + 4 * GS];
            loadrow(r2, oA);
            process(r0);
            j += GS; if (j >= k) break;
            oA = s_off[wave][j + 4 * GS];
            loadrow(r0, oB);
            process(r1);
            j += GS; if (j >= k) break;
            oB = s_off[wave][j + 4 * GS];
            loadrow(r1, oC);
            process(r2);
            j += GS;
        }
    }

#pragma unroll
    for (int mask = 8; mask <= 32; mask <<= 1) {
        const float m2 = __shfl_xor(m, mask, 64);
        const float s2 = __shfl_xor(s, mask, 64);
        float4 a2[2];
#pragma unroll
        for (int i = 0; i < 2; ++i) {
            a2[i].x = __shfl_xor(acc[i].x, mask, 64);
            a2[i].y = __shfl_xor(acc[i].y, mask, 64);
            a2[i].z = __shfl_xor(acc[i].z, mask, 64);
            a2[i].w = __shfl_xor(acc[i].w, mask, 64);
        }
        const float mm = fmaxf(m, m2);
        const float f1 = (m  == mm) ? 1.0f : __expf(m  - mm);
        const float f2 = (m2 == mm) ? 1.0f : __expf(m2 - mm);
        s = s * f1 + s2 * f2;
#pragma unroll
        for (int i = 0; i < 2; ++i) {
            acc[i].x = acc[i].x * f1 + a2[i].x * f2;
            acc[i].y = acc[i].y * f1 + a2[i].y * f2;
            acc[i].z = acc[i].z * f1 + a2[i].z * f2;
            acc[i].w = acc[i].w * f1 + a2[i].w * f2;
        }
        m = mm;
    }

    if (s > 0.0f) {
        if (grp == 0) {
            const float4* bias4 = (const float4*)bias;
            const float inv = 1.0f / s;
#pragma unroll
            for (int i = 0; i < 2; ++i) {
                const float4 bi = bias4[gl + 8 * i];
                float4 o;
                o.x = acc[i].x * inv + bi.x;
                o.y = acc[i].y * inv + bi.y;
                o.z = acc[i].z * inv + bi.z;
                o.w = acc[i].w * inv + bi.w;
                ((float4*)out)[((size_t)b * N_ + n) * V + gl + 8 * i] = o;
            }
        }
    } else {
        const float4* hb4 = (const float4*)hb;
        const int sl = lane % V;
        const int rs = lane / V;
        float4 a = {0.0f, 0.0f, 0.0f, 0.0f};
        for (int row = rs; row < N_; row += 4) {
            float4 v = hb4[(size_t)row * V + sl];
            a.x += v.x; a.y += v.y; a.z += v.z; a.w += v.w;
        }
#pragma unroll
        for (int mask = 16; mask <= 32; mask <<= 1) {
            a.x += __shfl_xor(a.x, mask, 64);
            a.y += __shfl_xor(a.y, mask, 64);
            a.z += __shfl_xor(a.z, mask, 64);
            a.w += __shfl_xor(a.w, mask, 64);
        }
        if (lane < V) {
            constexpr float invN = 1.0f / (float)N_;
            const float4 bi = ((const float4*)bias)[sl];
            float4 o;
            o.x = a.x * invN + bi.x;
            o.y = a.y * invN + bi.y;
            o.z = a.z * invN + bi.z;
            o.w = a.w * invN + bi.w;
            ((float4*)out)[((size_t)b * N_ + n) * V + sl] = o;
        }
    }
}

// ---------------------------------------------------------------------------
// Launch
// ---------------------------------------------------------------------------
extern "C" void kernel_launch(void* const* d_in, const int* in_sizes, int n_in,
                              void* d_out, int out_size, void* d_ws, size_t ws_size,
                              hipStream_t stream) {
    (void)in_sizes; (void)n_in; (void)out_size; (void)ws_size;

    const float* flow_x = (const float*)d_in[0];
    const float* graph  = (const float*)d_in[1];
    const float* W1     = (const float*)d_in[2];
    const float* b1     = (const float*)d_in[3];
    const float* W2     = (const float*)d_in[4];
    const float* b2     = (const float*)d_in[5];
    float* out = (float*)d_out;

    char* p = (char*)d_ws;
    auto carve = [&](size_t bytes) -> void* {
        void* r = (void*)p;
        p += (bytes + 255) & ~(size_t)255;
        return r;
    };
    int*   nbr_cnt = (int*)carve((size_t)N_ * sizeof(int));
    int*   nbr_idx = (int*)carve((size_t)N_ * MAXDEG * sizeof(int));
    float* h1      = (float*)carve((size_t)B_ * N_ * DHID * sizeof(float));
    void*  h1b     = carve((size_t)B_ * N_ * DHID * 2);   // bf16 copy
    float* x2      = (float*)carve((size_t)B_ * N_ * DHID * sizeof(float));
    float* h2      = (float*)carve((size_t)B_ * N_ * DOUT2 * sizeof(float));

    // 1. adjacency -> neighbor lists
    k_build_csr<<<N_ / 4, 256, 0, stream>>>(graph, nbr_cnt, nbr_idx);

    // 2. layer 1 linear: fp32 h1 + bf16 h1b (dual write)
    k_linear1<<<(B_ * N_) / 32, 256, 0, stream>>>(flow_x, W1, h1, h1b);

    // 3. layer 1 attention: bf16 gather/score (GS=4 lazy), fp32 acc -> x2
    k_attn1<<<N_ * B_ / 4, 256, 0, stream>>>(h1b, h1, nbr_cnt, nbr_idx, b1, x2);

    // 4. layer 2 linear (fp32)
    k_linear<DHID, DOUT2><<<(B_ * N_) / 32, 256, 0, stream>>>(x2, W2, h2);

    // 5. layer 2 attention (fp32) -> d_out  ([B,N,1,64] flat-identical)
    k_attn2<<<N_ * B_ / 4, 256, 0, stream>>>(h2, nbr_cnt, nbr_idx, b2, out);
}

// Round 7
// 224.073 us; speedup vs baseline: 1.1033x; 1.0620x over previous
//
#include <hip/hip_runtime.h>
#include <cmath>

// Problem constants
#define B_   8
#define N_   4096
#define DIN1 64
#define DHID 128
#define DOUT2 64
#define MAXDEG 256

// ---------------- bf16 helpers (RNE pack, shift unpack) --------------------
__device__ __forceinline__ unsigned pack2bf(float a, float b) {
    unsigned ua = __float_as_uint(a), ub = __float_as_uint(b);
    ua = (ua + 0x7FFFu + ((ua >> 16) & 1u)) >> 16;
    ub = (ub + 0x7FFFu + ((ub >> 16) & 1u)) & 0xFFFF0000u;
    return ua | ub;          // lo half = a, hi half = b
}
__device__ __forceinline__ float2 unpack2bf(unsigned u) {
    return {__uint_as_float(u << 16), __uint_as_float(u & 0xFFFF0000u)};
}
// LAZY unpack: hi element keeps the low-16 garbage bits (<=2^-7 relative
// mantissa perturbation, exponent untouched -> finite stays finite).
// Deterministic; used identically for q-init and loop -> self score exact.
__device__ __forceinline__ float2 lazy2bf(unsigned u) {
    return {__uint_as_float(u << 16), __uint_as_float(u)};
}

template <int SH>
__device__ __forceinline__ float dpp_shr_add(float p) {
    int t = __builtin_amdgcn_update_dpp(0, __float_as_int(p),
                                        0x110 | SH, 0xF, 0xF, true);
    return p + __int_as_float(t);
}
// Row-sum lands on the TOP lane of each GRPL-lane subgroup.
template <int GRPL>
__device__ __forceinline__ float dpp_reduce(float p) {
    if constexpr (GRPL == 16) p = dpp_shr_add<8>(p);
    p = dpp_shr_add<4>(p);
    p = dpp_shr_add<2>(p);
    p = dpp_shr_add<1>(p);
    return p;   // valid on lane GRPL-1 of each subgroup
}

// ---------------------------------------------------------------------------
// Kernel 1: adjacency -> neighbor lists. Wave per row, ballot compaction.
// ---------------------------------------------------------------------------
__global__ __launch_bounds__(256) void k_build_csr(
    const float* __restrict__ graph, int* __restrict__ cnt, int* __restrict__ idx)
{
    const int wave = threadIdx.x >> 6;
    const int lane = threadIdx.x & 63;
    const int n = blockIdx.x * 4 + wave;
    const unsigned long long below_mask = (1ULL << lane) - 1ULL;

    const float4* __restrict__ row4 = (const float4*)(graph + (size_t)n * N_);
    int* __restrict__ myidx = idx + (size_t)n * MAXDEG;

    int base = 0;
    for (int it = 0; it < N_ / 256; ++it) {
        const int i4 = it * 64 + lane;
        float4 g = row4[i4];
        const int e = 4 * i4;
#pragma unroll
        for (int c = 0; c < 4; ++c) {
            const float gc = (c == 0) ? g.x : (c == 1) ? g.y : (c == 2) ? g.z : g.w;
            const unsigned long long mk = __ballot(gc != 0.0f);
            const int pos = base + __popcll(mk & below_mask);
            if (gc != 0.0f && pos < MAXDEG) myidx[pos] = e + c;
            base += __popcll(mk);
        }
    }
    if (lane == 0) cnt[n] = (base < MAXDEG) ? base : MAXDEG;
}

// ---------------------------------------------------------------------------
// Kernel 2a: linear1 with DUAL WRITE: fp32 h1 (exact) + bf16 h1b. [proven]
// ---------------------------------------------------------------------------
__global__ __launch_bounds__(256) void k_linear1(
    const float* __restrict__ x, const float* __restrict__ W,
    float* __restrict__ out, void* __restrict__ outb)
{
    constexpr int DIN = DIN1, DOUT = DHID;
    constexpr int CG = DOUT / 4;      // 32
    constexpr int RG = 256 / CG;      // 8
    constexpr int TR = 32 / RG;       // 4

    __shared__ float sWt[DIN][DOUT + 4];

    const int t = threadIdx.x;
    const float4* W4 = (const float4*)W;
    for (int i = t; i < DOUT * (DIN / 4); i += 256) {
        int kk = i / (DIN / 4);
        int d4 = i % (DIN / 4);
        float4 w = W4[i];
        sWt[4 * d4 + 0][kk] = w.x;
        sWt[4 * d4 + 1][kk] = w.y;
        sWt[4 * d4 + 2][kk] = w.z;
        sWt[4 * d4 + 3][kk] = w.w;
    }
    __syncthreads();

    const int rg = t / CG;
    const int c  = t % CG;
    const int base = blockIdx.x * 32;
    const float4* x4 = (const float4*)x;

    float acc[TR][4];
#pragma unroll
    for (int i = 0; i < TR; ++i)
#pragma unroll
        for (int j = 0; j < 4; ++j) acc[i][j] = 0.0f;

    for (int d4 = 0; d4 < DIN / 4; ++d4) {
        float4 xf[TR];
#pragma unroll
        for (int i = 0; i < TR; ++i)
            xf[i] = x4[(size_t)(base + rg * TR + i) * (DIN / 4) + d4];
        float4 wf[4];
#pragma unroll
        for (int dd = 0; dd < 4; ++dd)
            wf[dd] = *(const float4*)&sWt[4 * d4 + dd][4 * c];
#pragma unroll
        for (int i = 0; i < TR; ++i) {
            acc[i][0] += xf[i].x * wf[0].x + xf[i].y * wf[1].x + xf[i].z * wf[2].x + xf[i].w * wf[3].x;
            acc[i][1] += xf[i].x * wf[0].y + xf[i].y * wf[1].y + xf[i].z * wf[2].y + xf[i].w * wf[3].y;
            acc[i][2] += xf[i].x * wf[0].z + xf[i].y * wf[1].z + xf[i].z * wf[2].z + xf[i].w * wf[3].z;
            acc[i][3] += xf[i].x * wf[0].w + xf[i].y * wf[1].w + xf[i].z * wf[2].w + xf[i].w * wf[3].w;
        }
    }

#pragma unroll
    for (int i = 0; i < TR; ++i) {
        const size_t row = (size_t)(base + rg * TR + i);
        float4 o = {acc[i][0], acc[i][1], acc[i][2], acc[i][3]};
        ((float4*)out)[row * CG + c] = o;
        uint2 ob = {pack2bf(o.x, o.y), pack2bf(o.z, o.w)};
        *(uint2*)((char*)outb + row * (DOUT * 2) + c * 8) = ob;
    }
}

// ---------------------------------------------------------------------------
// Kernel 2b: plain fp32 register-tiled linear (layer 2). [proven]
// ---------------------------------------------------------------------------
template <int DIN, int DOUT>
__global__ __launch_bounds__(256) void k_linear(
    const float* __restrict__ x, const float* __restrict__ W,
    float* __restrict__ out)
{
    constexpr int CG = DOUT / 4;
    constexpr int RG = 256 / CG;
    constexpr int TR = 32 / RG;

    __shared__ float sWt[DIN][DOUT + 4];

    const int t = threadIdx.x;
    const float4* W4 = (const float4*)W;
    for (int i = t; i < DOUT * (DIN / 4); i += 256) {
        int kk = i / (DIN / 4);
        int d4 = i % (DIN / 4);
        float4 w = W4[i];
        sWt[4 * d4 + 0][kk] = w.x;
        sWt[4 * d4 + 1][kk] = w.y;
        sWt[4 * d4 + 2][kk] = w.z;
        sWt[4 * d4 + 3][kk] = w.w;
    }
    __syncthreads();

    const int rg = t / CG;
    const int c  = t % CG;
    const int base = blockIdx.x * 32;
    const float4* x4 = (const float4*)x;

    float acc[TR][4];
#pragma unroll
    for (int i = 0; i < TR; ++i)
#pragma unroll
        for (int j = 0; j < 4; ++j) acc[i][j] = 0.0f;

    for (int d4 = 0; d4 < DIN / 4; ++d4) {
        float4 xf[TR];
#pragma unroll
        for (int i = 0; i < TR; ++i)
            xf[i] = x4[(size_t)(base + rg * TR + i) * (DIN / 4) + d4];
        float4 wf[4];
#pragma unroll
        for (int dd = 0; dd < 4; ++dd)
            wf[dd] = *(const float4*)&sWt[4 * d4 + dd][4 * c];
#pragma unroll
        for (int i = 0; i < TR; ++i) {
            acc[i][0] += xf[i].x * wf[0].x + xf[i].y * wf[1].x + xf[i].z * wf[2].x + xf[i].w * wf[3].x;
            acc[i][1] += xf[i].x * wf[0].y + xf[i].y * wf[1].y + xf[i].z * wf[2].y + xf[i].w * wf[3].y;
            acc[i][2] += xf[i].x * wf[0].z + xf[i].y * wf[1].z + xf[i].z * wf[2].z + xf[i].w * wf[3].z;
            acc[i][3] += xf[i].x * wf[0].w + xf[i].y * wf[1].w + xf[i].z * wf[2].w + xf[i].w * wf[3].w;
        }
    }

#pragma unroll
    for (int i = 0; i < TR; ++i) {
        float4 o = {acc[i][0], acc[i][1], acc[i][2], acc[i][3]};
        ((float4*)out)[(size_t)(base + rg * TR + i) * CG + c] = o;
    }
}

// ---------------------------------------------------------------------------
// Kernel 3a: attn layer-1 — GS=4 lazy-bf16 (passing R6 version, unchanged).
// ---------------------------------------------------------------------------
__global__ __launch_bounds__(256) void k_attn1(
    const void* __restrict__ h16, const float* __restrict__ h32,
    const int* __restrict__ cnt, const int* __restrict__ idx,
    const float* __restrict__ bias, float* __restrict__ out)
{
    constexpr int RBb = DHID * 2;   // bf16 row bytes (256)
    constexpr int RBf = DHID * 4;   // fp32 row bytes (512)
    constexpr int GS  = 4;          // 4 streams of 16 lanes

    const int bid  = blockIdx.x;
    const int b    = bid & 7;                    // batch -> XCD pinning
    const int wave = threadIdx.x >> 6;
    const int lane = threadIdx.x & 63;
    const int n    = (bid >> 3) * 4 + wave;      // one query per wave
    const int grp  = lane >> 4;
    const int gl   = lane & 15;
    const int gtop = lane | 15;

    __shared__ int s_off[4][MAXDEG + 48];        // bf16 byte offsets

    const int k = cnt[n];
    const int* __restrict__ myidx = idx + (size_t)n * MAXDEG;
    for (int j = lane; j < k; j += 64) s_off[wave][j] = myidx[j] * RBb;
    for (int z = k + lane; z < k + 48; z += 64) s_off[wave][z] = 0;

    const char*  __restrict__ hb = (const char*)h16 + (size_t)b * N_ * RBb;
    const char*  __restrict__ hf = (const char*)h32 + (size_t)b * N_ * RBf;
    const int lb = gl * 16;                      // lane's bf16 byte slot (8 dims)

    // q fragment: 8 dims per lane, LAZY-unpacked bf16 -> 4 float2
    float2 qc[4];
    {
        const uint4 qu = *(const uint4*)(hb + (size_t)n * RBb + lb);
        qc[0] = lazy2bf(qu.x); qc[1] = lazy2bf(qu.y);
        qc[2] = lazy2bf(qu.z); qc[3] = lazy2bf(qu.w);
    }

    // fixed-order dot: two float2 chains (pk_fma-friendly); identical
    // sequence for self-init and loop -> bit-exact self score
    auto dotc = [&](const float2* c) -> float {
        float2 pa = {0.0f, 0.0f}, pb2 = {0.0f, 0.0f};
        pa.x  += qc[0].x * c[0].x;  pa.y  += qc[0].y * c[0].y;
        pb2.x += qc[1].x * c[1].x;  pb2.y += qc[1].y * c[1].y;
        pa.x  += qc[2].x * c[2].x;  pa.y  += qc[2].y * c[2].y;
        pb2.x += qc[3].x * c[3].x;  pb2.y += qc[3].y * c[3].y;
        return (pa.x + pa.y) + (pb2.x + pb2.y);
    };

    // self-score init: m = ||q_lazy||^2 (identical op order to loop dot)
    float m;
    {
        float p = dotc(qc);
        p = dpp_reduce<16>(p);
        const float pb = __shfl(p, gtop, 64);
        m = (pb != 0.0f) ? pb : -INFINITY;
    }
    float mt = m - 100.0f;
    float s = 0.0f;
    float acc8[8];
#pragma unroll
    for (int i = 0; i < 8; ++i) acc8[i] = 0.0f;

    // taken path accumulates from the FP32 row (off is the bf16 offset;
    // fp32 offset = 2*off since RBf = 2*RBb)
    auto process = [&](const uint4 cur, int off) {
        float2 c[4] = {lazy2bf(cur.x), lazy2bf(cur.y),
                       lazy2bf(cur.z), lazy2bf(cur.w)};
        float p = dotc(c);
        p = dpp_reduce<16>(p);
        if (__builtin_expect((__ballot(p > mt) & 0x8000800080008000ULL) != 0ULL, 0)) {
            const float pb = __shfl(p, gtop, 64);
            const bool valid = (pb != 0.0f);      // dot==0 => masked (torch)
            const float pm   = valid ? pb : m;
            const float newm = fmaxf(m, pm);
            const float f = (m == newm) ? 1.0f : __expf(m - newm);
            const float e = valid ? __expf(pb - newm) : 0.0f;
            s = s * f + e;
            // fp32 reload of this row's lane slice (dims [8gl, 8gl+8))
            const float4* fr = (const float4*)(hf + 2 * (size_t)off) + 2 * gl;
            const float4 lo = fr[0], hi = fr[1];
            const float f8[8] = {lo.x, lo.y, lo.z, lo.w, hi.x, hi.y, hi.z, hi.w};
#pragma unroll
            for (int i = 0; i < 8; ++i) acc8[i] = acc8[i] * f + e * f8[i];
            m = newm;
            mt = m - 100.0f;
        }
    };

    // depth-2 data + depth-4 offset pipeline; per-buffer offsets carried
    {
        uint4 r0, r1, r2;
        int u0, u1, u2, oA, oB, oC;
        oA = s_off[wave][grp + 2 * GS];
        oB = s_off[wave][grp + 3 * GS];
        u0 = s_off[wave][grp];
        r0 = *(const uint4*)(hb + u0 + lb);
        u1 = s_off[wave][grp + GS];
        r1 = *(const uint4*)(hb + u1 + lb);
        int j = grp;
        while (j < k) {
            oC = s_off[wave][j + 4 * GS];
            u2 = oA; r2 = *(const uint4*)(hb + u2 + lb);
            process(r0, u0);
            j += GS; if (j >= k) break;
            oA = s_off[wave][j + 4 * GS];
            u0 = oB; r0 = *(const uint4*)(hb + u0 + lb);
            process(r1, u1);
            j += GS; if (j >= k) break;
            oB = s_off[wave][j + 4 * GS];
            u1 = oC; r1 = *(const uint4*)(hb + u1 + lb);
            process(r2, u2);
            j += GS;
        }
    }

    // merge the 4 subgroup states (xor 16, 32)
#pragma unroll
    for (int mask = 16; mask <= 32; mask <<= 1) {
        const float m2 = __shfl_xor(m, mask, 64);
        const float s2 = __shfl_xor(s, mask, 64);
        float a2[8];
#pragma unroll
        for (int i = 0; i < 8; ++i) a2[i] = __shfl_xor(acc8[i], mask, 64);
        const float mm = fmaxf(m, m2);
        const float f1 = (m  == mm) ? 1.0f : __expf(m  - mm);
        const float f2 = (m2 == mm) ? 1.0f : __expf(m2 - mm);
        s = s * f1 + s2 * f2;
#pragma unroll
        for (int i = 0; i < 8; ++i) acc8[i] = acc8[i] * f1 + a2[i] * f2;
        m = mm;
    }

    if (s > 0.0f) {
        if (grp == 0) {
            const float4* bias4 = (const float4*)bias;
            const float4 b0 = bias4[2 * gl], b1 = bias4[2 * gl + 1];
            const float bi[8] = {b0.x, b0.y, b0.z, b0.w, b1.x, b1.y, b1.z, b1.w};
            const float inv = 1.0f / s;
            float4 lo, hi;
            lo.x = fmaxf(acc8[0] * inv + bi[0], 0.0f);
            lo.y = fmaxf(acc8[1] * inv + bi[1], 0.0f);
            lo.z = fmaxf(acc8[2] * inv + bi[2], 0.0f);
            lo.w = fmaxf(acc8[3] * inv + bi[3], 0.0f);
            hi.x = fmaxf(acc8[4] * inv + bi[4], 0.0f);
            hi.y = fmaxf(acc8[5] * inv + bi[5], 0.0f);
            hi.z = fmaxf(acc8[6] * inv + bi[6], 0.0f);
            hi.w = fmaxf(acc8[7] * inv + bi[7], 0.0f);
            float4* orow = (float4*)out + ((size_t)b * N_ + n) * (DHID / 4) + 2 * gl;
            orow[0] = lo;
            orow[1] = hi;
        }
    } else {
        // RARE (all masked): uniform softmax -> column mean of fp32 h[b]
        const float4* hf4 = (const float4*)hf;
        const int sl = lane % 32;
        const int rs = lane / 32;
        float4 a = {0.0f, 0.0f, 0.0f, 0.0f};
        for (int row = rs; row < N_; row += 2) {
            float4 v = hf4[(size_t)row * 32 + sl];
            a.x += v.x; a.y += v.y; a.z += v.z; a.w += v.w;
        }
        a.x += __shfl_xor(a.x, 32, 64);
        a.y += __shfl_xor(a.y, 32, 64);
        a.z += __shfl_xor(a.z, 32, 64);
        a.w += __shfl_xor(a.w, 32, 64);
        if (lane < 32) {
            constexpr float invN = 1.0f / (float)N_;
            const float4 bi = ((const float4*)bias)[sl];
            float4 o;
            o.x = fmaxf(a.x * invN + bi.x, 0.0f);
            o.y = fmaxf(a.y * invN + bi.y, 0.0f);
            o.z = fmaxf(a.z * invN + bi.z, 0.0f);
            o.w = fmaxf(a.w * invN + bi.w, 0.0f);
            ((float4*)out)[((size_t)b * N_ + n) * 32 + sl] = o;
        }
    }
}

// ---------------------------------------------------------------------------
// Kernel 3b: attn layer-2, fp32, NOW on the GS=4/16-lane skeleton (the
// structure that reaches ~91% VALUBusy in attn1, vs 59% for the 8-lane
// version): lane gl owns dims [4gl,4gl+4) -> ONE float4 load per row per
// lane (was two), 4-FMA dot in two chains, dpp_reduce<16>. Scoring stays
// pure fp32 (required: h2 rows can be near-identical); init and loop share
// the identical dot sequence -> self/masked/one-hot semantics preserved;
// accumulate uses the same loaded fp32 registers (exact).
// ---------------------------------------------------------------------------
__global__ __launch_bounds__(256) void k_attn2(
    const float* __restrict__ h, const int* __restrict__ cnt,
    const int* __restrict__ idx, const float* __restrict__ bias,
    float* __restrict__ out)
{
    constexpr int D  = DOUT2;
    constexpr int V  = D / 4;                    // 16
    constexpr int GS = 4;                        // 4 streams of 16 lanes
    constexpr int RB = D * 4;                    // 256

    const int bid  = blockIdx.x;
    const int b    = bid & 7;
    const int wave = threadIdx.x >> 6;
    const int lane = threadIdx.x & 63;
    const int n    = (bid >> 3) * 4 + wave;
    const int grp  = lane >> 4;
    const int gl   = lane & 15;
    const int gtop = lane | 15;

    __shared__ int s_off[4][MAXDEG + 48];

    const int k = cnt[n];
    const int* __restrict__ myidx = idx + (size_t)n * MAXDEG;
    for (int j = lane; j < k; j += 64) s_off[wave][j] = myidx[j] * RB;
    for (int z = k + lane; z < k + 48; z += 64) s_off[wave][z] = 0;

    const char* __restrict__ hb = (const char*)h + (size_t)b * N_ * RB;
    const int lb = gl * 16;                      // dims [4gl, 4gl+4)

    float4 qf;
    qf = *(const float4*)(hb + (size_t)n * RB + lb);

    // fixed-order dot: two 2-FMA chains; identical sequence in init and loop
    auto dotc = [&](const float4 c) -> float {
        float pa = qf.x * c.x, pb2 = qf.y * c.y;
        pa += qf.z * c.z;      pb2 += qf.w * c.w;
        return pa + pb2;
    };

    float m;
    {
        float p = dotc(qf);
        p = dpp_reduce<16>(p);
        const float pb = __shfl(p, gtop, 64);
        m = (pb != 0.0f) ? pb : -INFINITY;
    }
    float mt = m - 100.0f;
    float s = 0.0f;
    float4 acc = {0.0f, 0.0f, 0.0f, 0.0f};

    auto process = [&](const float4 cur) {
        float p = dotc(cur);
        p = dpp_reduce<16>(p);
        if (__builtin_expect((__ballot(p > mt) & 0x8000800080008000ULL) != 0ULL, 0)) {
            const float pb = __shfl(p, gtop, 64);
            const bool valid = (pb != 0.0f);
            const float pm   = valid ? pb : m;
            const float newm = fmaxf(m, pm);
            const float f = (m == newm) ? 1.0f : __expf(m - newm);
            const float e = valid ? __expf(pb - newm) : 0.0f;
            s = s * f + e;
            acc.x = acc.x * f + e * cur.x;
            acc.y = acc.y * f + e * cur.y;
            acc.z = acc.z * f + e * cur.z;
            acc.w = acc.w * f + e * cur.w;
            m = newm;
            mt = m - 100.0f;
        }
    };

    // depth-2 data + depth-4 offset pipeline (attn1's proven rotation)
    {
        float4 r0, r1, r2;
        int oA, oB, oC;
        oA = s_off[wave][grp + 2 * GS];
        oB = s_off[wave][grp + 3 * GS];
        r0 = *(const float4*)(hb + s_off[wave][grp] + lb);
        r1 = *(const float4*)(hb + s_off[wave][grp + GS] + lb);
        int j = grp;
        while (j < k) {
            oC = s_off[wave][j + 4 * GS];
            r2 = *(const float4*)(hb + oA + lb);
            process(r0);
            j += GS; if (j >= k) break;
            oA = s_off[wave][j + 4 * GS];
            r0 = *(const float4*)(hb + oB + lb);
            process(r1);
            j += GS; if (j >= k) break;
            oB = s_off[wave][j + 4 * GS];
            r1 = *(const float4*)(hb + oC + lb);
            process(r2);
            j += GS;
        }
    }

    // merge the 4 subgroup states (xor 16, 32)
#pragma unroll
    for (int mask = 16; mask <= 32; mask <<= 1) {
        const float m2 = __shfl_xor(m, mask, 64);
        const float s2 = __shfl_xor(s, mask, 64);
        float4 a2;
        a2.x = __shfl_xor(acc.x, mask, 64);
        a2.y = __shfl_xor(acc.y, mask, 64);
        a2.z = __shfl_xor(acc.z, mask, 64);
        a2.w = __shfl_xor(acc.w, mask, 64);
        const float mm = fmaxf(m, m2);
        const float f1 = (m  == mm) ? 1.0f : __expf(m  - mm);
        const float f2 = (m2 == mm) ? 1.0f : __expf(m2 - mm);
        s = s * f1 + s2 * f2;
        acc.x = acc.x * f1 + a2.x * f2;
        acc.y = acc.y * f1 + a2.y * f2;
        acc.z = acc.z * f1 + a2.z * f2;
        acc.w = acc.w * f1 + a2.w * f2;
        m = mm;
    }

    if (s > 0.0f) {
        if (grp == 0) {
            const float4 bi = ((const float4*)bias)[gl];
            const float inv = 1.0f / s;
            float4 o;
            o.x = acc.x * inv + bi.x;
            o.y = acc.y * inv + bi.y;
            o.z = acc.z * inv + bi.z;
            o.w = acc.w * inv + bi.w;
            ((float4*)out)[((size_t)b * N_ + n) * V + gl] = o;
        }
    } else {
        const float4* hb4 = (const float4*)hb;
        const int sl = lane % V;
        const int rs = lane / V;
        float4 a = {0.0f, 0.0f, 0.0f, 0.0f};
        for (int row = rs; row < N_; row += 4) {
            float4 v = hb4[(size_t)row * V + sl];
            a.x += v.x; a.y += v.y; a.z += v.z; a.w += v.w;
        }
#pragma unroll
        for (int mask = 16; mask <= 32; mask <<= 1) {
            a.x += __shfl_xor(a.x, mask, 64);
            a.y += __shfl_xor(a.y, mask, 64);
            a.z += __shfl_xor(a.z, mask, 64);
            a.w += __shfl_xor(a.w, mask, 64);
        }
        if (lane < V) {
            constexpr float invN = 1.0f / (float)N_;
            const float4 bi = ((const float4*)bias)[sl];
            float4 o;
            o.x = a.x * invN + bi.x;
            o.y = a.y * invN + bi.y;
            o.z = a.z * invN + bi.z;
            o.w = a.w * invN + bi.w;
            ((float4*)out)[((size_t)b * N_ + n) * V + sl] = o;
        }
    }
}

// ---------------------------------------------------------------------------
// Launch
// ---------------------------------------------------------------------------
extern "C" void kernel_launch(void* const* d_in, const int* in_sizes, int n_in,
                              void* d_out, int out_size, void* d_ws, size_t ws_size,
                              hipStream_t stream) {
    (void)in_sizes; (void)n_in; (void)out_size; (void)ws_size;

    const float* flow_x = (const float*)d_in[0];
    const float* graph  = (const float*)d_in[1];
    const float* W1     = (const float*)d_in[2];
    const float* b1     = (const float*)d_in[3];
    const float* W2     = (const float*)d_in[4];
    const float* b2     = (const float*)d_in[5];
    float* out = (float*)d_out;

    char* p = (char*)d_ws;
    auto carve = [&](size_t bytes) -> void* {
        void* r = (void*)p;
        p += (bytes + 255) & ~(size_t)255;
        return r;
    };
    int*   nbr_cnt = (int*)carve((size_t)N_ * sizeof(int));
    int*   nbr_idx = (int*)carve((size_t)N_ * MAXDEG * sizeof(int));
    float* h1      = (float*)carve((size_t)B_ * N_ * DHID * sizeof(float));
    void*  h1b     = carve((size_t)B_ * N_ * DHID * 2);   // bf16 copy
    float* x2      = (float*)carve((size_t)B_ * N_ * DHID * sizeof(float));
    float* h2      = (float*)carve((size_t)B_ * N_ * DOUT2 * sizeof(float));

    // 1. adjacency -> neighbor lists
    k_build_csr<<<N_ / 4, 256, 0, stream>>>(graph, nbr_cnt, nbr_idx);

    // 2. layer 1 linear: fp32 h1 + bf16 h1b (dual write)
    k_linear1<<<(B_ * N_) / 32, 256, 0, stream>>>(flow_x, W1, h1, h1b);

    // 3. layer 1 attention: bf16 gather/score (GS=4 lazy), fp32 acc -> x2
    k_attn1<<<N_ * B_ / 4, 256, 0, stream>>>(h1b, h1, nbr_cnt, nbr_idx, b1, x2);

    // 4. layer 2 linear (fp32)
    k_linear<DHID, DOUT2><<<(B_ * N_) / 32, 256, 0, stream>>>(x2, W2, h2);

    // 5. layer 2 attention (fp32, GS=4) -> d_out  ([B,N,1,64] flat)
    k_attn2<<<N_ * B_ / 4, 256, 0, stream>>>(h2, nbr_cnt, nbr_idx, b2, out);
}